// Round 1
// baseline (2231.964 us; speedup 1.0000x reference)
//
#include <hip/hip_runtime.h>
#include <hip/hip_bf16.h>

// ---------------------------------------------------------------------------
// GraphSAGE 2-layer (mean agg) + edge MLP predictor, fp32 baseline.
// score[e] = (h2 @ Wp_top)[src[e]] + (h2 @ Wp_bot)[dst[e]] + bp
// ---------------------------------------------------------------------------

__global__ void k_deg(const int* __restrict__ dst, float* __restrict__ deg, int E) {
    int e = blockIdx.x * blockDim.x + threadIdx.x;
    if (e < E) atomicAdd(&deg[dst[e]], 1.0f);
}

__global__ void k_invdeg(const float* __restrict__ deg, float* __restrict__ invdeg, int N) {
    int n = blockIdx.x * blockDim.x + threadIdx.x;
    if (n < N) invdeg[n] = 1.0f / fmaxf(deg[n], 1.0f);
}

// One thread per (edge, 16-byte chunk): gather src row, atomic-scatter to dst row.
__global__ void k_scatter(const float4* __restrict__ X4, const int* __restrict__ src,
                          const int* __restrict__ dst, float* __restrict__ agg, int E) {
    int gid = blockIdx.x * blockDim.x + threadIdx.x;
    int e = gid >> 5;
    if (e >= E) return;
    int q = gid & 31;
    float4 v = X4[(size_t)src[e] * 32 + q];
    float* base = &agg[(size_t)dst[e] * 128 + q * 4];
    atomicAdd(base + 0, v.x);
    atomicAdd(base + 1, v.y);
    atomicAdd(base + 2, v.z);
    atomicAdd(base + 3, v.w);
}

// Fused node GEMM: OUT = act( A @ Wself + (AGG*invdeg) @ Wneigh + bias )
// Treated as [N,256] @ [256,128] with K-concat; K staged in 4 phases of 64.
// Block = 256 threads, 64 nodes per block. Each lane: 16 nodes x 2 dims.
__global__ __launch_bounds__(256) void k_gemm(
    const float* __restrict__ A, const float* __restrict__ AGG,
    const float* __restrict__ invdeg,
    const float* __restrict__ Wself, const float* __restrict__ Wneigh,
    const float* __restrict__ bias, float* __restrict__ OUT,
    int N, int do_relu)
{
    __shared__ float sW[64][128];   // 32 KB: K-phase of the concat weight
    __shared__ float sA[64][68];    // ~17 KB: 64 nodes x 64 k (padded, 16B-aligned rows)
    const int t = threadIdx.x;
    const int wave = t >> 6, lane = t & 63;
    const int nodeBase = blockIdx.x * 64;

    float acc[16][2];
#pragma unroll
    for (int n = 0; n < 16; ++n) { acc[n][0] = 0.f; acc[n][1] = 0.f; }

    for (int kt = 0; kt < 4; ++kt) {
        const float* Wsrc = (kt < 2) ? Wself : Wneigh;
        const int rowBase = (kt & 1) * 64;

        // stage W rows [rowBase, rowBase+64) : 8192 floats, 8 float4 per thread
#pragma unroll
        for (int i = 0; i < 8; ++i) {
            int idx = i * 256 + t;
            int r = idx >> 5;
            int c = (idx & 31) << 2;
            *(float4*)&sW[r][c] = *(const float4*)&Wsrc[(rowBase + r) * 128 + c];
        }
        // stage A tile: 64 nodes x 64 k, 4 float4 per thread
#pragma unroll
        for (int i = 0; i < 4; ++i) {
            int idx = i * 256 + t;
            int n = idx >> 4;
            int q = (idx & 15) << 2;
            int gn = nodeBase + n;
            float4 v = make_float4(0.f, 0.f, 0.f, 0.f);
            if (gn < N) {
                if (kt < 2) {
                    v = *(const float4*)&A[(size_t)gn * 128 + rowBase + q];
                } else {
                    v = *(const float4*)&AGG[(size_t)gn * 128 + rowBase + q];
                    float s = invdeg[gn];
                    v.x *= s; v.y *= s; v.z *= s; v.w *= s;
                }
            }
            *(float4*)&sA[n][q] = v;
        }
        __syncthreads();

        const int nb = wave * 16;
        for (int k4 = 0; k4 < 16; ++k4) {
            float2 wv0 = *(const float2*)&sW[k4 * 4 + 0][2 * lane];
            float2 wv1 = *(const float2*)&sW[k4 * 4 + 1][2 * lane];
            float2 wv2 = *(const float2*)&sW[k4 * 4 + 2][2 * lane];
            float2 wv3 = *(const float2*)&sW[k4 * 4 + 3][2 * lane];
#pragma unroll
            for (int n = 0; n < 16; ++n) {
                float4 av = *(const float4*)&sA[nb + n][k4 * 4];  // wave-broadcast
                acc[n][0] += av.x * wv0.x + av.y * wv1.x + av.z * wv2.x + av.w * wv3.x;
                acc[n][1] += av.x * wv0.y + av.y * wv1.y + av.z * wv2.y + av.w * wv3.y;
            }
        }
        __syncthreads();
    }

    const float b0 = bias[2 * lane], b1v = bias[2 * lane + 1];
#pragma unroll
    for (int n = 0; n < 16; ++n) {
        int gn = nodeBase + wave * 16 + n;
        if (gn < N) {
            float ox = acc[n][0] + b0, oy = acc[n][1] + b1v;
            if (do_relu) { ox = fmaxf(ox, 0.f); oy = fmaxf(oy, 0.f); }
            *(float2*)&OUT[(size_t)gn * 128 + 2 * lane] = make_float2(ox, oy);
        }
    }
}

// Per-node projections: ps = h2 @ Wp[:128,:], pd = h2 @ Wp[128:,:]  (one wave/node)
__global__ __launch_bounds__(256) void k_nodeproj(
    const float* __restrict__ h2, const float* __restrict__ Wp,
    float4* __restrict__ ps4, float4* __restrict__ pd4, int N)
{
    int gw = (blockIdx.x * blockDim.x + threadIdx.x) >> 6;
    int lane = threadIdx.x & 63;
    if (gw >= N) return;
    float2 hv = *(const float2*)&h2[(size_t)gw * 128 + 2 * lane];
    int r0 = 2 * lane, r1 = 2 * lane + 1;
    float p0 = hv.x * Wp[r0 * 3 + 0] + hv.y * Wp[r1 * 3 + 0];
    float p1 = hv.x * Wp[r0 * 3 + 1] + hv.y * Wp[r1 * 3 + 1];
    float p2 = hv.x * Wp[r0 * 3 + 2] + hv.y * Wp[r1 * 3 + 2];
    float q0 = hv.x * Wp[(128 + r0) * 3 + 0] + hv.y * Wp[(128 + r1) * 3 + 0];
    float q1 = hv.x * Wp[(128 + r0) * 3 + 1] + hv.y * Wp[(128 + r1) * 3 + 1];
    float q2 = hv.x * Wp[(128 + r0) * 3 + 2] + hv.y * Wp[(128 + r1) * 3 + 2];
#pragma unroll
    for (int off = 32; off; off >>= 1) {
        p0 += __shfl_xor(p0, off, 64);
        p1 += __shfl_xor(p1, off, 64);
        p2 += __shfl_xor(p2, off, 64);
        q0 += __shfl_xor(q0, off, 64);
        q1 += __shfl_xor(q1, off, 64);
        q2 += __shfl_xor(q2, off, 64);
    }
    if (lane == 0) {
        ps4[gw] = make_float4(p0, p1, p2, 0.f);
        pd4[gw] = make_float4(q0, q1, q2, 0.f);
    }
}

__global__ void k_edge(const float4* __restrict__ ps4, const float4* __restrict__ pd4,
                       const int* __restrict__ src, const int* __restrict__ dst,
                       const float* __restrict__ bp, float* __restrict__ out, int E)
{
    int e = blockIdx.x * blockDim.x + threadIdx.x;
    if (e >= E) return;
    float4 a = ps4[src[e]];
    float4 b = pd4[dst[e]];
    out[(size_t)e * 3 + 0] = a.x + b.x + bp[0];
    out[(size_t)e * 3 + 1] = a.y + b.y + bp[1];
    out[(size_t)e * 3 + 2] = a.z + b.z + bp[2];
}

extern "C" void kernel_launch(void* const* d_in, const int* in_sizes, int n_in,
                              void* d_out, int out_size, void* d_ws, size_t ws_size,
                              hipStream_t stream)
{
    const float* x   = (const float*)d_in[0];
    // d_in[1] = e (edge features) — unused by the reference score
    const int*   src = (const int*)d_in[2];
    const int*   dst = (const int*)d_in[3];
    const float* W1s = (const float*)d_in[4];
    const float* W1n = (const float*)d_in[5];
    const float* b1  = (const float*)d_in[6];
    const float* W2s = (const float*)d_in[7];
    const float* W2n = (const float*)d_in[8];
    const float* b2  = (const float*)d_in[9];
    const float* Wp  = (const float*)d_in[10];
    const float* bp  = (const float*)d_in[11];
    const int N = in_sizes[0] / 128;
    const int E = in_sizes[2];
    float* out = (float*)d_out;

    float* ws     = (float*)d_ws;
    float* deg    = ws;                          // N
    float* invdeg = deg + N;                     // N
    float* agg    = invdeg + N;                  // N*128
    float* h      = agg + (size_t)N * 128;       // N*128
    float* h2     = h + (size_t)N * 128;         // N*128
    float* ps4    = h2 + (size_t)N * 128;        // N*4
    float* pd4    = ps4 + (size_t)N * 4;         // N*4

    hipMemsetAsync(deg, 0, (size_t)N * 4, stream);
    hipMemsetAsync(agg, 0, (size_t)N * 128 * 4, stream);

    k_deg<<<(E + 255) / 256, 256, 0, stream>>>(dst, deg, E);
    k_invdeg<<<(N + 255) / 256, 256, 0, stream>>>(deg, invdeg, N);

    // layer 1
    k_scatter<<<(E * 32 + 255) / 256, 256, 0, stream>>>((const float4*)x, src, dst, agg, E);
    k_gemm<<<(N + 63) / 64, 256, 0, stream>>>(x, agg, invdeg, W1s, W1n, b1, h, N, 1);

    // layer 2
    hipMemsetAsync(agg, 0, (size_t)N * 128 * 4, stream);
    k_scatter<<<(E * 32 + 255) / 256, 256, 0, stream>>>((const float4*)h, src, dst, agg, E);
    k_gemm<<<(N + 63) / 64, 256, 0, stream>>>(h, agg, invdeg, W2s, W2n, b2, h2, N, 0);

    // edge scoring via per-node projections
    k_nodeproj<<<(N + 3) / 4, 256, 0, stream>>>(h2, Wp, (float4*)ps4, (float4*)pd4, N);
    k_edge<<<(E + 255) / 256, 256, 0, stream>>>((const float4*)ps4, (const float4*)pd4,
                                                src, dst, bp, out, E);
}

// Round 2
// 474.326 us; speedup vs baseline: 4.7056x; 4.7056x over previous
//
#include <hip/hip_runtime.h>
#include <hip/hip_bf16.h>

// ---------------------------------------------------------------------------
// GraphSAGE 2-layer (mean agg) + edge MLP predictor.
// Round 2: CSR-by-dst gather aggregation (no fp32 atomics), projection fused
// into layer-2 GEMM epilogue (h2 never materialized).
// score[e] = (h2 @ Wp_top)[src[e]] + (h2 @ Wp_bot)[dst[e]] + bp
// ---------------------------------------------------------------------------

__global__ void k_deg(const int* __restrict__ dst, float* __restrict__ fdeg, int E) {
    int e = blockIdx.x * blockDim.x + threadIdx.x;
    if (e < E) atomicAdd(&fdeg[dst[e]], 1.0f);
}

// Single-block exclusive scan of (int)fdeg -> cursor; also invdeg.
__global__ __launch_bounds__(1024) void k_scan(const float* __restrict__ fdeg,
                                               int* __restrict__ cursor,
                                               float* __restrict__ invdeg, int N) {
    __shared__ int buf[1024];
    __shared__ int carry;
    if (threadIdx.x == 0) carry = 0;
    __syncthreads();
    for (int base = 0; base < N; base += 1024) {
        int i = base + threadIdx.x;
        int v = (i < N) ? (int)fdeg[i] : 0;
        buf[threadIdx.x] = v;
        __syncthreads();
        int sum = v;
        for (int ofs = 1; ofs < 1024; ofs <<= 1) {
            int t = (threadIdx.x >= (unsigned)ofs) ? buf[threadIdx.x - ofs] : 0;
            __syncthreads();
            sum += t;
            buf[threadIdx.x] = sum;
            __syncthreads();
        }
        if (i < N) {
            cursor[i] = carry + sum - v;  // exclusive prefix
            invdeg[i] = 1.0f / fmaxf((float)v, 1.0f);
        }
        __syncthreads();
        if (threadIdx.x == 1023) carry += buf[1023];
        __syncthreads();
    }
}

// Bucket edges: eidx[pos] = src[e], pos = cursor[dst[e]]++. After this,
// cursor[i] == start_i + deg_i (end offset).
__global__ void k_fill(const int* __restrict__ src, const int* __restrict__ dst,
                       int* __restrict__ cursor, int* __restrict__ eidx, int E) {
    int e = blockIdx.x * blockDim.x + threadIdx.x;
    if (e < E) {
        int p = atomicAdd(&cursor[dst[e]], 1);
        eidx[p] = src[e];
    }
}

// Mean aggregation as a gather: one wave per dst node; lane covers 2 dims.
__global__ __launch_bounds__(256) void k_agg(const float* __restrict__ X,
                                             const int* __restrict__ eidx,
                                             const int* __restrict__ cursor,
                                             const float* __restrict__ fdeg,
                                             const float* __restrict__ invdeg,
                                             float* __restrict__ OUT, int N) {
    int w = (blockIdx.x * blockDim.x + threadIdx.x) >> 6;
    int lane = threadIdx.x & 63;
    if (w >= N) return;
    int d = (int)fdeg[w];
    int o = cursor[w] - d;  // start offset (cursor holds end after k_fill)
    float2 a0 = make_float2(0.f, 0.f), a1 = make_float2(0.f, 0.f);
    int j = 0;
    for (; j + 2 <= d; j += 2) {
        int s0 = eidx[o + j], s1 = eidx[o + j + 1];
        float2 v0 = *(const float2*)&X[(size_t)s0 * 128 + lane * 2];
        float2 v1 = *(const float2*)&X[(size_t)s1 * 128 + lane * 2];
        a0.x += v0.x; a0.y += v0.y;
        a1.x += v1.x; a1.y += v1.y;
    }
    if (j < d) {
        int s0 = eidx[o + j];
        float2 v0 = *(const float2*)&X[(size_t)s0 * 128 + lane * 2];
        a0.x += v0.x; a0.y += v0.y;
    }
    float sc = invdeg[w];
    *(float2*)&OUT[(size_t)w * 128 + lane * 2] =
        make_float2((a0.x + a1.x) * sc, (a0.y + a1.y) * sc);
}

// Fused node GEMM: pre = A @ Wself + (AGG) @ Wneigh + bias   (AGG pre-scaled)
// MODE 0: OUT[n] = relu(pre)   MODE 1: ps/pd[n] = pre @ Wp_top/bot (h2 not stored)
// [N,256] @ [256,128] with K staged in 4 phases of 64. Block = 256 thr, 64 nodes.
template <int MODE>
__global__ __launch_bounds__(256) void k_gemm(
    const float* __restrict__ A, const float* __restrict__ AGG,
    const float* __restrict__ Wself, const float* __restrict__ Wneigh,
    const float* __restrict__ bias, const float* __restrict__ Wp,
    float* __restrict__ OUT, float* __restrict__ ps4, float* __restrict__ pd4,
    int N)
{
    __shared__ float sW[64][128];   // 32 KB
    __shared__ float sA[64][68];    // ~17 KB (padded rows, 16B aligned)
    const int t = threadIdx.x;
    const int wave = t >> 6, lane = t & 63;
    const int nodeBase = blockIdx.x * 64;

    float acc[16][2];
#pragma unroll
    for (int n = 0; n < 16; ++n) { acc[n][0] = 0.f; acc[n][1] = 0.f; }

    for (int kt = 0; kt < 4; ++kt) {
        const float* Wsrc = (kt < 2) ? Wself : Wneigh;
        const int rowBase = (kt & 1) * 64;
        const float* Asrc = (kt < 2) ? A : AGG;

#pragma unroll
        for (int i = 0; i < 8; ++i) {
            int idx = i * 256 + t;
            int r = idx >> 5;
            int c = (idx & 31) << 2;
            *(float4*)&sW[r][c] = *(const float4*)&Wsrc[(rowBase + r) * 128 + c];
        }
#pragma unroll
        for (int i = 0; i < 4; ++i) {
            int idx = i * 256 + t;
            int n = idx >> 4;
            int q = (idx & 15) << 2;
            int gn = nodeBase + n;
            float4 v = make_float4(0.f, 0.f, 0.f, 0.f);
            if (gn < N) v = *(const float4*)&Asrc[(size_t)gn * 128 + rowBase + q];
            *(float4*)&sA[n][q] = v;
        }
        __syncthreads();

        const int nb = wave * 16;
        for (int k4 = 0; k4 < 16; ++k4) {
            float2 wv0 = *(const float2*)&sW[k4 * 4 + 0][2 * lane];
            float2 wv1 = *(const float2*)&sW[k4 * 4 + 1][2 * lane];
            float2 wv2 = *(const float2*)&sW[k4 * 4 + 2][2 * lane];
            float2 wv3 = *(const float2*)&sW[k4 * 4 + 3][2 * lane];
#pragma unroll
            for (int n = 0; n < 16; ++n) {
                float4 av = *(const float4*)&sA[nb + n][k4 * 4];  // wave-broadcast
                acc[n][0] += av.x * wv0.x + av.y * wv1.x + av.z * wv2.x + av.w * wv3.x;
                acc[n][1] += av.x * wv0.y + av.y * wv1.y + av.z * wv2.y + av.w * wv3.y;
            }
        }
        __syncthreads();
    }

    const float b0 = bias[2 * lane], b1v = bias[2 * lane + 1];

    if (MODE == 0) {
#pragma unroll
        for (int n = 0; n < 16; ++n) {
            int gn = nodeBase + wave * 16 + n;
            if (gn < N) {
                float ox = fmaxf(acc[n][0] + b0, 0.f);
                float oy = fmaxf(acc[n][1] + b1v, 0.f);
                *(float2*)&OUT[(size_t)gn * 128 + 2 * lane] = make_float2(ox, oy);
            }
        }
    } else {
        // fused projection: ps = h2 @ Wp[:128], pd = h2 @ Wp[128:]
        float wps[3][2], wpd[3][2];
        const int r0 = 2 * lane, r1 = 2 * lane + 1;
#pragma unroll
        for (int k = 0; k < 3; ++k) {
            wps[k][0] = Wp[r0 * 3 + k];
            wps[k][1] = Wp[r1 * 3 + k];
            wpd[k][0] = Wp[(128 + r0) * 3 + k];
            wpd[k][1] = Wp[(128 + r1) * 3 + k];
        }
#pragma unroll
        for (int n = 0; n < 16; ++n) {
            float h0 = acc[n][0] + b0;
            float h1 = acc[n][1] + b1v;
            float p[6];
#pragma unroll
            for (int k = 0; k < 3; ++k) {
                p[k]     = h0 * wps[k][0] + h1 * wps[k][1];
                p[3 + k] = h0 * wpd[k][0] + h1 * wpd[k][1];
            }
#pragma unroll
            for (int off = 32; off; off >>= 1) {
#pragma unroll
                for (int k = 0; k < 6; ++k) p[k] += __shfl_xor(p[k], off, 64);
            }
            int gn = nodeBase + wave * 16 + n;
            if (lane == 0 && gn < N) {
                *(float4*)&ps4[(size_t)gn * 4] = make_float4(p[0], p[1], p[2], 0.f);
                *(float4*)&pd4[(size_t)gn * 4] = make_float4(p[3], p[4], p[5], 0.f);
            }
        }
    }
}

__global__ void k_edge(const float4* __restrict__ ps4, const float4* __restrict__ pd4,
                       const int* __restrict__ src, const int* __restrict__ dst,
                       const float* __restrict__ bp, float* __restrict__ out, int E)
{
    int e = blockIdx.x * blockDim.x + threadIdx.x;
    if (e >= E) return;
    float4 a = ps4[src[e]];
    float4 b = pd4[dst[e]];
    out[(size_t)e * 3 + 0] = a.x + b.x + bp[0];
    out[(size_t)e * 3 + 1] = a.y + b.y + bp[1];
    out[(size_t)e * 3 + 2] = a.z + b.z + bp[2];
}

extern "C" void kernel_launch(void* const* d_in, const int* in_sizes, int n_in,
                              void* d_out, int out_size, void* d_ws, size_t ws_size,
                              hipStream_t stream)
{
    const float* x   = (const float*)d_in[0];
    // d_in[1] = e (edge features) — unused by the reference score
    const int*   src = (const int*)d_in[2];
    const int*   dst = (const int*)d_in[3];
    const float* W1s = (const float*)d_in[4];
    const float* W1n = (const float*)d_in[5];
    const float* b1  = (const float*)d_in[6];
    const float* W2s = (const float*)d_in[7];
    const float* W2n = (const float*)d_in[8];
    const float* b2  = (const float*)d_in[9];
    const float* Wp  = (const float*)d_in[10];
    const float* bp  = (const float*)d_in[11];
    const int N = in_sizes[0] / 128;
    const int E = in_sizes[2];
    float* out = (float*)d_out;

    // workspace carve (~56 MB)
    float* fdeg   = (float*)d_ws;                 // N
    float* invdeg = fdeg + N;                     // N
    int*   cursor = (int*)(invdeg + N);           // N
    int*   eidx   = cursor + N;                   // E
    float* agg    = (float*)(eidx + E);           // N*128
    float* h      = agg + (size_t)N * 128;        // N*128
    float* ps4    = h + (size_t)N * 128;          // N*4
    float* pd4    = ps4 + (size_t)N * 4;          // N*4

    hipMemsetAsync(fdeg, 0, (size_t)N * 4, stream);

    // CSR build (once; serves both layers)
    k_deg<<<(E + 255) / 256, 256, 0, stream>>>(dst, fdeg, E);
    k_scan<<<1, 1024, 0, stream>>>(fdeg, cursor, invdeg, N);
    k_fill<<<(E + 255) / 256, 256, 0, stream>>>(src, dst, cursor, eidx, E);

    // layer 1: mean-agg(x) -> agg ; h = relu(x@W1s + agg@W1n + b1)
    k_agg<<<(N + 3) / 4, 256, 0, stream>>>(x, eidx, cursor, fdeg, invdeg, agg, N);
    k_gemm<0><<<(N + 63) / 64, 256, 0, stream>>>(x, agg, W1s, W1n, b1, nullptr,
                                                 h, nullptr, nullptr, N);

    // layer 2: mean-agg(h) -> agg ; ps/pd = (h@W2s + agg@W2n + b2) @ Wp halves
    k_agg<<<(N + 3) / 4, 256, 0, stream>>>(h, eidx, cursor, fdeg, invdeg, agg, N);
    k_gemm<1><<<(N + 63) / 64, 256, 0, stream>>>(h, agg, W2s, W2n, b2, Wp,
                                                 nullptr, ps4, pd4, N);

    // edge scoring
    k_edge<<<(E + 255) / 256, 256, 0, stream>>>((const float4*)ps4, (const float4*)pd4,
                                                src, dst, bp, out, E);
}

// Round 4
// 244.034 us; speedup vs baseline: 9.1461x; 1.9437x over previous
//
#include <hip/hip_runtime.h>
#include <hip/hip_bf16.h>

// ---------------------------------------------------------------------------
// GraphSAGE 2-layer (mean agg) + edge MLP predictor.
// Round 4: fix compile (manual bf16 pack, no __builtin_bit_cast on class).
// bf16 features (fp32 accumulate) for gather + MFMA GEMM; multi-block scan.
// score[e] = (h2 @ Wp_top)[src[e]] + (h2 @ Wp_bot)[dst[e]] + bp
// ---------------------------------------------------------------------------

typedef __attribute__((ext_vector_type(8))) short bf16x8;
typedef __attribute__((ext_vector_type(4))) float f32x4;

static __device__ __forceinline__ float bf16lo(unsigned u) {
    return __uint_as_float(u << 16);
}
static __device__ __forceinline__ float bf16hi(unsigned u) {
    return __uint_as_float(u & 0xffff0000u);
}
static __device__ __forceinline__ unsigned short f2bf(float f) {
    unsigned u = __float_as_uint(f);
    unsigned r = 0x7fffu + ((u >> 16) & 1u);  // round to nearest even
    return (unsigned short)((u + r) >> 16);
}
static __device__ __forceinline__ unsigned pack_bf162(float a, float b) {
    return (unsigned)f2bf(a) | ((unsigned)f2bf(b) << 16);
}

// ---------------- degree ----------------
__global__ void k_deg(const int* __restrict__ dst, float* __restrict__ fdeg, int E) {
    int e = blockIdx.x * blockDim.x + threadIdx.x;
    if (e < E) atomicAdd(&fdeg[dst[e]], 1.0f);
}

// ---------------- 3-phase exclusive scan (1024 elems / block) ----------------
__global__ __launch_bounds__(256) void k_scan1(const float* __restrict__ fdeg,
                                               int* __restrict__ cursor,
                                               float* __restrict__ invdeg,
                                               int* __restrict__ partials, int N) {
    __shared__ int wsum[4];
    const int t = threadIdx.x;
    const int i0 = blockIdx.x * 1024 + t * 4;
    int d[4];
#pragma unroll
    for (int j = 0; j < 4; ++j) {
        int i = i0 + j;
        float f = (i < N) ? fdeg[i] : 0.f;
        d[j] = (int)f;
        if (i < N) invdeg[i] = 1.0f / fmaxf(f, 1.0f);
    }
    int s = d[0] + d[1] + d[2] + d[3];
    int incl = s;
#pragma unroll
    for (int off = 1; off < 64; off <<= 1) {
        int u = __shfl_up(incl, off, 64);
        if ((t & 63) >= off) incl += u;
    }
    if ((t & 63) == 63) wsum[t >> 6] = incl;
    __syncthreads();
    int woff = 0;
#pragma unroll
    for (int w = 0; w < 4; ++w)
        if (w < (t >> 6)) woff += wsum[w];
    int p = (incl - s) + woff;
#pragma unroll
    for (int j = 0; j < 4; ++j) {
        int i = i0 + j;
        if (i < N) cursor[i] = p;
        p += d[j];
    }
    if (t == 255) partials[blockIdx.x] = woff + incl;
}

__global__ void k_scan2(int* __restrict__ partials, int nb) {  // 1 block, 64 thr
    int t = threadIdx.x;
    int carry = 0;
    for (int base = 0; base < nb; base += 64) {
        int i = base + t;
        int v = (i < nb) ? partials[i] : 0;
        int incl = v;
#pragma unroll
        for (int off = 1; off < 64; off <<= 1) {
            int u = __shfl_up(incl, off, 64);
            if (t >= off) incl += u;
        }
        if (i < nb) partials[i] = carry + incl - v;
        carry += __shfl(incl, 63, 64);
    }
}

__global__ __launch_bounds__(256) void k_scan3(int* __restrict__ cursor,
                                               const int* __restrict__ partials, int N) {
    int off = partials[blockIdx.x];
    int i0 = blockIdx.x * 1024 + threadIdx.x * 4;
#pragma unroll
    for (int j = 0; j < 4; ++j) {
        int i = i0 + j;
        if (i < N) cursor[i] += off;
    }
}

// ---------------- CSR fill ----------------
__global__ void k_fill(const int* __restrict__ src, const int* __restrict__ dst,
                       int* __restrict__ cursor, int* __restrict__ eidx, int E) {
    int e = blockIdx.x * blockDim.x + threadIdx.x;
    if (e < E) {
        int p = atomicAdd(&cursor[dst[e]], 1);
        eidx[p] = src[e];
    }
}

// ---------------- fp32 -> bf16 convert ----------------
__global__ __launch_bounds__(256) void k_cvt(const float* __restrict__ X,
                                             unsigned short* __restrict__ Xb, int n4) {
    int i = blockIdx.x * blockDim.x + threadIdx.x;
    if (i < n4) {
        float4 v = ((const float4*)X)[i];
        uint2 o;
        o.x = pack_bf162(v.x, v.y);
        o.y = pack_bf162(v.z, v.w);
        *(uint2*)(Xb + (size_t)i * 4) = o;
    }
}

// ---------------- weight prep: Wt[n][k] = bf16(concat(Ws,Wn)[k][n]) ----------------
__global__ __launch_bounds__(256) void k_prepW(const float* __restrict__ Ws,
                                               const float* __restrict__ Wn,
                                               unsigned short* __restrict__ Wt) {
    int id = blockIdx.x * blockDim.x + threadIdx.x;  // 32768 total
    if (id >= 128 * 256) return;
    int k = id >> 7, n = id & 127;
    float v = (k < 128) ? Ws[k * 128 + n] : Wn[(k - 128) * 128 + n];
    Wt[n * 256 + k] = f2bf(v);
}

// ---------------- mean aggregation (bf16 gather, fp32 acc, bf16 out) -------
// One wave per dst node; half-wave per edge (32 lanes x 8B = 256B row).
__global__ __launch_bounds__(256) void k_agg(const unsigned short* __restrict__ Xb,
                                             const int* __restrict__ eidx,
                                             const int* __restrict__ cursor,
                                             const float* __restrict__ fdeg,
                                             const float* __restrict__ invdeg,
                                             unsigned short* __restrict__ OUT, int N) {
    int w = (blockIdx.x * blockDim.x + threadIdx.x) >> 6;
    int lane = threadIdx.x & 63;
    if (w >= N) return;
    int d = (int)fdeg[w];
    int o = cursor[w] - d;  // cursor holds end offset after k_fill
    int half = lane >> 5, q = lane & 31;
    float4 acc = make_float4(0.f, 0.f, 0.f, 0.f);
    for (int j = 0; j < d; j += 2) {
        int je = j + half;
        if (je < d) {
            int s = eidx[o + je];
            uint2 v = *(const uint2*)(Xb + (size_t)s * 128 + q * 4);
            acc.x += bf16lo(v.x);
            acc.y += bf16hi(v.x);
            acc.z += bf16lo(v.y);
            acc.w += bf16hi(v.y);
        }
    }
    acc.x += __shfl_xor(acc.x, 32, 64);
    acc.y += __shfl_xor(acc.y, 32, 64);
    acc.z += __shfl_xor(acc.z, 32, 64);
    acc.w += __shfl_xor(acc.w, 32, 64);
    if (half == 0) {
        float sc = invdeg[w];
        uint2 ov;
        ov.x = pack_bf162(acc.x * sc, acc.y * sc);
        ov.y = pack_bf162(acc.z * sc, acc.w * sc);
        *(uint2*)(OUT + (size_t)w * 128 + q * 4) = ov;
    }
}

// ---------------- MFMA node GEMM -------------------------------------------
// OUT[n][128] = act( [A0|A1][n][256] @ Wt^T + bias ), bf16 in/out, fp32 acc.
// Block: 256 thr (4 waves), 128 nodes. Wave: 32 rows x 128 cols.
// Wt (256x128 as [n][k], 64KB bf16) staged in LDS, XOR-swizzled (G4).
__global__ __launch_bounds__(256) void k_gemm_mfma(
    const unsigned short* __restrict__ A0, const unsigned short* __restrict__ A1,
    const unsigned short* __restrict__ Wt, const float* __restrict__ bias,
    unsigned short* __restrict__ OUT, int N, int do_relu)
{
    __shared__ __align__(16) char sW[65536];  // Wt swizzled: 128 rows x 512B
    const int t = threadIdx.x;

    // stage all of Wt: 16 iters x 256 thr x 16B
#pragma unroll
    for (int i = 0; i < 16; ++i) {
        int o = (i * 256 + t) * 16;
        int n = o >> 9;
        int c = o & 511;
        int sw = (n << 9) | (c ^ ((n & 7) << 4));
        *(float4*)&sW[sw] = *(const float4*)((const char*)Wt + o);
    }

    const int wave = t >> 6, lane = t & 63;
    const int nodeBase = blockIdx.x * 128 + wave * 32;
    const int lrow = lane & 15, lk = lane >> 4;

    f32x4 acc[2][8];
#pragma unroll
    for (int rs = 0; rs < 2; ++rs)
#pragma unroll
        for (int nb = 0; nb < 8; ++nb) acc[rs][nb] = (f32x4){0.f, 0.f, 0.f, 0.f};

    __syncthreads();

    const int r0 = nodeBase + lrow, r1 = nodeBase + 16 + lrow;
    for (int ks = 0; ks < 8; ++ks) {
        const unsigned short* Asrc = (ks < 4) ? A0 : A1;
        const int kk = (ks & 3) * 32 + lk * 8;
        bf16x8 a0 = {}, a1 = {};
        if (r0 < N) a0 = *(const bf16x8*)(Asrc + (size_t)r0 * 128 + kk);
        if (r1 < N) a1 = *(const bf16x8*)(Asrc + (size_t)r1 * 128 + kk);
        const int cbase = ks * 64 + lk * 16;  // byte col within 512B row
#pragma unroll
        for (int nb = 0; nb < 8; ++nb) {
            int n = nb * 16 + lrow;
            int sw = (n << 9) | (cbase ^ ((n & 7) << 4));
            bf16x8 b = *(const bf16x8*)&sW[sw];
            acc[0][nb] = __builtin_amdgcn_mfma_f32_16x16x32_bf16(a0, b, acc[0][nb], 0, 0, 0);
            acc[1][nb] = __builtin_amdgcn_mfma_f32_16x16x32_bf16(a1, b, acc[1][nb], 0, 0, 0);
        }
    }

    // C/D layout: col = lane&15, row = (lane>>4)*4 + reg  [m89-verified]
#pragma unroll
    for (int rs = 0; rs < 2; ++rs) {
#pragma unroll
        for (int nb = 0; nb < 8; ++nb) {
            int col = nb * 16 + lrow;
            float bv = bias[col];
#pragma unroll
            for (int r = 0; r < 4; ++r) {
                int node = nodeBase + rs * 16 + lk * 4 + r;
                if (node < N) {
                    float v = acc[rs][nb][r] + bv;
                    if (do_relu) v = fmaxf(v, 0.f);
                    OUT[(size_t)node * 128 + col] = f2bf(v);
                }
            }
        }
    }
}

// ---------------- per-node projections: ps/pd = h2 @ Wp halves --------------
__global__ __launch_bounds__(256) void k_nodeproj(
    const unsigned short* __restrict__ h2b, const float* __restrict__ Wp,
    float4* __restrict__ ps4, float4* __restrict__ pd4, int N)
{
    int w = (blockIdx.x * blockDim.x + threadIdx.x) >> 6;
    int lane = threadIdx.x & 63;
    if (w >= N) return;
    unsigned v = *(const unsigned*)(h2b + (size_t)w * 128 + lane * 2);
    float h0 = bf16lo(v), h1 = bf16hi(v);
    int r0 = 2 * lane, r1 = 2 * lane + 1;
    float p[6];
#pragma unroll
    for (int k = 0; k < 3; ++k) {
        p[k]     = h0 * Wp[r0 * 3 + k] + h1 * Wp[r1 * 3 + k];
        p[3 + k] = h0 * Wp[(128 + r0) * 3 + k] + h1 * Wp[(128 + r1) * 3 + k];
    }
#pragma unroll
    for (int off = 32; off; off >>= 1) {
#pragma unroll
        for (int k = 0; k < 6; ++k) p[k] += __shfl_xor(p[k], off, 64);
    }
    if (lane == 0) {
        ps4[w] = make_float4(p[0], p[1], p[2], 0.f);
        pd4[w] = make_float4(p[3], p[4], p[5], 0.f);
    }
}

__global__ void k_edge(const float4* __restrict__ ps4, const float4* __restrict__ pd4,
                       const int* __restrict__ src, const int* __restrict__ dst,
                       const float* __restrict__ bp, float* __restrict__ out, int E)
{
    int e = blockIdx.x * blockDim.x + threadIdx.x;
    if (e >= E) return;
    float4 a = ps4[src[e]];
    float4 b = pd4[dst[e]];
    out[(size_t)e * 3 + 0] = a.x + b.x + bp[0];
    out[(size_t)e * 3 + 1] = a.y + b.y + bp[1];
    out[(size_t)e * 3 + 2] = a.z + b.z + bp[2];
}

extern "C" void kernel_launch(void* const* d_in, const int* in_sizes, int n_in,
                              void* d_out, int out_size, void* d_ws, size_t ws_size,
                              hipStream_t stream)
{
    const float* x   = (const float*)d_in[0];
    // d_in[1] = e (edge features) — unused by the reference score
    const int*   src = (const int*)d_in[2];
    const int*   dst = (const int*)d_in[3];
    const float* W1s = (const float*)d_in[4];
    const float* W1n = (const float*)d_in[5];
    const float* b1  = (const float*)d_in[6];
    const float* W2s = (const float*)d_in[7];
    const float* W2n = (const float*)d_in[8];
    const float* b2  = (const float*)d_in[9];
    const float* Wp  = (const float*)d_in[10];
    const float* bp  = (const float*)d_in[11];
    const int N = in_sizes[0] / 128;
    const int E = in_sizes[2];
    float* out = (float*)d_out;

    // ---- workspace carve (256B aligned chunks) ----
    char* wsp = (char*)d_ws;
    auto alloc = [&](size_t bytes) { char* p = wsp; wsp += (bytes + 255) & ~(size_t)255; return p; };
    float* fdeg     = (float*)alloc((size_t)N * 4);
    float* invdeg   = (float*)alloc((size_t)N * 4);
    int*   cursor   = (int*)alloc((size_t)N * 4);
    int*   eidx     = (int*)alloc((size_t)E * 4);
    int*   partials = (int*)alloc(4096);
    unsigned short* xb   = (unsigned short*)alloc((size_t)N * 128 * 2);
    unsigned short* aggb = (unsigned short*)alloc((size_t)N * 128 * 2);
    unsigned short* hb   = (unsigned short*)alloc((size_t)N * 128 * 2);
    unsigned short* h2b  = (unsigned short*)alloc((size_t)N * 128 * 2);
    unsigned short* Wt1  = (unsigned short*)alloc(256 * 128 * 2);
    unsigned short* Wt2  = (unsigned short*)alloc(256 * 128 * 2);
    float* ps4 = (float*)alloc((size_t)N * 16);
    float* pd4 = (float*)alloc((size_t)N * 16);

    const int scanBlocks = (N + 1023) / 1024;

    (void)hipMemsetAsync(fdeg, 0, (size_t)N * 4, stream);

    // CSR build
    k_deg<<<(E + 255) / 256, 256, 0, stream>>>(dst, fdeg, E);
    k_scan1<<<scanBlocks, 256, 0, stream>>>(fdeg, cursor, invdeg, partials, N);
    k_scan2<<<1, 64, 0, stream>>>(partials, scanBlocks);
    k_scan3<<<scanBlocks, 256, 0, stream>>>(cursor, partials, N);
    k_fill<<<(E + 255) / 256, 256, 0, stream>>>(src, dst, cursor, eidx, E);

    // feature & weight prep
    k_cvt<<<(N * 32 + 255) / 256, 256, 0, stream>>>(x, xb, N * 32);
    k_prepW<<<128, 256, 0, stream>>>(W1s, W1n, Wt1);
    k_prepW<<<128, 256, 0, stream>>>(W2s, W2n, Wt2);

    // layer 1
    k_agg<<<(N + 3) / 4, 256, 0, stream>>>(xb, eidx, cursor, fdeg, invdeg, aggb, N);
    k_gemm_mfma<<<(N + 127) / 128, 256, 0, stream>>>(xb, aggb, Wt1, b1, hb, N, 1);

    // layer 2
    k_agg<<<(N + 3) / 4, 256, 0, stream>>>(hb, eidx, cursor, fdeg, invdeg, aggb, N);
    k_gemm_mfma<<<(N + 127) / 128, 256, 0, stream>>>(hb, aggb, Wt2, b2, h2b, N, 0);

    // edge scoring
    k_nodeproj<<<(N + 3) / 4, 256, 0, stream>>>(h2b, Wp, (float4*)ps4, (float4*)pd4, N);
    k_edge<<<(E + 255) / 256, 256, 0, stream>>>((const float4*)ps4, (const float4*)pd4,
                                                src, dst, bp, out, E);
}

// Round 5
// 232.298 us; speedup vs baseline: 9.6082x; 1.0505x over previous
//
#include <hip/hip_runtime.h>
#include <hip/hip_bf16.h>

// ---------------------------------------------------------------------------
// GraphSAGE 2-layer (mean agg) + edge MLP predictor.
// Round 5: layer-2 rank-3 factorization. Since layer 2 is linear and only
// consumed through ps/pd = h2 @ Wp halves, fold W2{s,n} @ Wp into Wc[128][12],
// project P = h @ Wc once, and aggregate 6 dims instead of 128.
// score[e] = ps[src] + pd[dst] + bconst,
//   ps[n] = P[n].u + mean_in(P[src].t),  pd[n] = P[n].v + mean_in(P[src].w)
// ---------------------------------------------------------------------------

typedef __attribute__((ext_vector_type(8))) short bf16x8;
typedef __attribute__((ext_vector_type(4))) float f32x4;

static __device__ __forceinline__ float bf16lo(unsigned u) {
    return __uint_as_float(u << 16);
}
static __device__ __forceinline__ float bf16hi(unsigned u) {
    return __uint_as_float(u & 0xffff0000u);
}
static __device__ __forceinline__ unsigned short f2bf(float f) {
    unsigned u = __float_as_uint(f);
    unsigned r = 0x7fffu + ((u >> 16) & 1u);  // round to nearest even
    return (unsigned short)((u + r) >> 16);
}
static __device__ __forceinline__ unsigned pack_bf162(float a, float b) {
    return (unsigned)f2bf(a) | ((unsigned)f2bf(b) << 16);
}

// ---------------- degree ----------------
__global__ void k_deg(const int* __restrict__ dst, float* __restrict__ fdeg, int E) {
    int e = blockIdx.x * blockDim.x + threadIdx.x;
    if (e < E) atomicAdd(&fdeg[dst[e]], 1.0f);
}

// ---------------- 3-phase exclusive scan (1024 elems / block) ----------------
__global__ __launch_bounds__(256) void k_scan1(const float* __restrict__ fdeg,
                                               int* __restrict__ cursor,
                                               float* __restrict__ invdeg,
                                               int* __restrict__ partials, int N) {
    __shared__ int wsum[4];
    const int t = threadIdx.x;
    const int i0 = blockIdx.x * 1024 + t * 4;
    int d[4];
#pragma unroll
    for (int j = 0; j < 4; ++j) {
        int i = i0 + j;
        float f = (i < N) ? fdeg[i] : 0.f;
        d[j] = (int)f;
        if (i < N) invdeg[i] = 1.0f / fmaxf(f, 1.0f);
    }
    int s = d[0] + d[1] + d[2] + d[3];
    int incl = s;
#pragma unroll
    for (int off = 1; off < 64; off <<= 1) {
        int u = __shfl_up(incl, off, 64);
        if ((t & 63) >= off) incl += u;
    }
    if ((t & 63) == 63) wsum[t >> 6] = incl;
    __syncthreads();
    int woff = 0;
#pragma unroll
    for (int w = 0; w < 4; ++w)
        if (w < (t >> 6)) woff += wsum[w];
    int p = (incl - s) + woff;
#pragma unroll
    for (int j = 0; j < 4; ++j) {
        int i = i0 + j;
        if (i < N) cursor[i] = p;
        p += d[j];
    }
    if (t == 255) partials[blockIdx.x] = woff + incl;
}

__global__ void k_scan2(int* __restrict__ partials, int nb) {  // 1 block, 64 thr
    int t = threadIdx.x;
    int carry = 0;
    for (int base = 0; base < nb; base += 64) {
        int i = base + t;
        int v = (i < nb) ? partials[i] : 0;
        int incl = v;
#pragma unroll
        for (int off = 1; off < 64; off <<= 1) {
            int u = __shfl_up(incl, off, 64);
            if (t >= off) incl += u;
        }
        if (i < nb) partials[i] = carry + incl - v;
        carry += __shfl(incl, 63, 64);
    }
}

__global__ __launch_bounds__(256) void k_scan3(int* __restrict__ cursor,
                                               const int* __restrict__ partials, int N) {
    int off = partials[blockIdx.x];
    int i0 = blockIdx.x * 1024 + threadIdx.x * 4;
#pragma unroll
    for (int j = 0; j < 4; ++j) {
        int i = i0 + j;
        if (i < N) cursor[i] += off;
    }
}

// ---------------- CSR fill ----------------
__global__ void k_fill(const int* __restrict__ src, const int* __restrict__ dst,
                       int* __restrict__ cursor, int* __restrict__ eidx, int E) {
    int e = blockIdx.x * blockDim.x + threadIdx.x;
    if (e < E) {
        int p = atomicAdd(&cursor[dst[e]], 1);
        eidx[p] = src[e];
    }
}

// ---------------- fp32 -> bf16 convert ----------------
__global__ __launch_bounds__(256) void k_cvt(const float* __restrict__ X,
                                             unsigned short* __restrict__ Xb, int n4) {
    int i = blockIdx.x * blockDim.x + threadIdx.x;
    if (i < n4) {
        float4 v = ((const float4*)X)[i];
        uint2 o;
        o.x = pack_bf162(v.x, v.y);
        o.y = pack_bf162(v.z, v.w);
        *(uint2*)(Xb + (size_t)i * 4) = o;
    }
}

// ---------------- weight prep ----------------------------------------------
// blocks 0..127: Wt1[n][k] = bf16(concat(W1s,W1n)[k][n])   (layer-1 MFMA B)
// block 128:     Wc[c][j]  (j: 0-2 u=W2s@Wp_top, 3-5 t=W2n@Wp_top,
//                              6-8 v=W2s@Wp_bot, 9-11 w=W2n@Wp_bot)
//                bconst[j] = bp[j] + b2@(Wp_top+Wp_bot)[:,j]
__global__ __launch_bounds__(256) void k_prep(
    const float* __restrict__ W1s, const float* __restrict__ W1n,
    unsigned short* __restrict__ Wt1,
    const float* __restrict__ W2s, const float* __restrict__ W2n,
    const float* __restrict__ Wp, const float* __restrict__ b2,
    const float* __restrict__ bp, float* __restrict__ Wc,
    float* __restrict__ bconst)
{
    int blk = blockIdx.x;
    if (blk < 128) {
        int id = blk * 256 + threadIdx.x;
        int k = id >> 7, n = id & 127;
        float v = (k < 128) ? W1s[k * 128 + n] : W1n[(k - 128) * 128 + n];
        Wt1[n * 256 + k] = f2bf(v);
    } else {
        for (int id = threadIdx.x; id < 1539; id += 256) {
            if (id < 1536) {
                int c = id / 12, j = id % 12;
                int q = j / 3, jj = j % 3;
                const float* W2 = (q == 0 || q == 2) ? W2s : W2n;
                int wpoff = (q < 2) ? 0 : 128;
                float s = 0.f;
                for (int m = 0; m < 128; ++m)
                    s += W2[c * 128 + m] * Wp[(wpoff + m) * 3 + jj];
                Wc[c * 12 + j] = s;
            } else {
                int jj = id - 1536;
                float s = bp[jj];
                for (int m = 0; m < 128; ++m)
                    s += b2[m] * (Wp[m * 3 + jj] + Wp[(128 + m) * 3 + jj]);
                bconst[jj] = s;
            }
        }
    }
}

// ---------------- mean aggregation (bf16 gather, fp32 acc, bf16 out) -------
// One wave per dst node; half-wave per edge (32 lanes x 8B = 256B row).
__global__ __launch_bounds__(256) void k_agg(const unsigned short* __restrict__ Xb,
                                             const int* __restrict__ eidx,
                                             const int* __restrict__ cursor,
                                             const float* __restrict__ fdeg,
                                             const float* __restrict__ invdeg,
                                             unsigned short* __restrict__ OUT, int N) {
    int w = (blockIdx.x * blockDim.x + threadIdx.x) >> 6;
    int lane = threadIdx.x & 63;
    if (w >= N) return;
    int d = (int)fdeg[w];
    int o = cursor[w] - d;  // cursor holds end offset after k_fill
    int half = lane >> 5, q = lane & 31;
    float4 acc = make_float4(0.f, 0.f, 0.f, 0.f);
    for (int j = 0; j < d; j += 2) {
        int je = j + half;
        if (je < d) {
            int s = eidx[o + je];
            uint2 v = *(const uint2*)(Xb + (size_t)s * 128 + q * 4);
            acc.x += bf16lo(v.x);
            acc.y += bf16hi(v.x);
            acc.z += bf16lo(v.y);
            acc.w += bf16hi(v.y);
        }
    }
    acc.x += __shfl_xor(acc.x, 32, 64);
    acc.y += __shfl_xor(acc.y, 32, 64);
    acc.z += __shfl_xor(acc.z, 32, 64);
    acc.w += __shfl_xor(acc.w, 32, 64);
    if (half == 0) {
        float sc = invdeg[w];
        uint2 ov;
        ov.x = pack_bf162(acc.x * sc, acc.y * sc);
        ov.y = pack_bf162(acc.z * sc, acc.w * sc);
        *(uint2*)(OUT + (size_t)w * 128 + q * 4) = ov;
    }
}

// ---------------- MFMA node GEMM (layer 1) ----------------------------------
// OUT[n][128] = relu( [A0|A1][n][256] @ Wt^T + bias ), bf16 in/out, fp32 acc.
// Block: 256 thr (4 waves), 128 nodes. Wave: 32 rows x 128 cols.
// Wt (256x128 as [n][k], 64KB bf16) staged in LDS, XOR-swizzled (G4).
__global__ __launch_bounds__(256) void k_gemm_mfma(
    const unsigned short* __restrict__ A0, const unsigned short* __restrict__ A1,
    const unsigned short* __restrict__ Wt, const float* __restrict__ bias,
    unsigned short* __restrict__ OUT, int N)
{
    __shared__ __align__(16) char sW[65536];  // Wt swizzled: 128 rows x 512B
    const int t = threadIdx.x;

#pragma unroll
    for (int i = 0; i < 16; ++i) {
        int o = (i * 256 + t) * 16;
        int n = o >> 9;
        int c = o & 511;
        int sw = (n << 9) | (c ^ ((n & 7) << 4));
        *(float4*)&sW[sw] = *(const float4*)((const char*)Wt + o);
    }

    const int wave = t >> 6, lane = t & 63;
    const int nodeBase = blockIdx.x * 128 + wave * 32;
    const int lrow = lane & 15, lk = lane >> 4;

    f32x4 acc[2][8];
#pragma unroll
    for (int rs = 0; rs < 2; ++rs)
#pragma unroll
        for (int nb = 0; nb < 8; ++nb) acc[rs][nb] = (f32x4){0.f, 0.f, 0.f, 0.f};

    __syncthreads();

    const int r0 = nodeBase + lrow, r1 = nodeBase + 16 + lrow;
    for (int ks = 0; ks < 8; ++ks) {
        const unsigned short* Asrc = (ks < 4) ? A0 : A1;
        const int kk = (ks & 3) * 32 + lk * 8;
        bf16x8 a0 = {}, a1 = {};
        if (r0 < N) a0 = *(const bf16x8*)(Asrc + (size_t)r0 * 128 + kk);
        if (r1 < N) a1 = *(const bf16x8*)(Asrc + (size_t)r1 * 128 + kk);
        const int cbase = ks * 64 + lk * 16;  // byte col within 512B row
#pragma unroll
        for (int nb = 0; nb < 8; ++nb) {
            int n = nb * 16 + lrow;
            int sw = (n << 9) | (cbase ^ ((n & 7) << 4));
            bf16x8 b = *(const bf16x8*)&sW[sw];
            acc[0][nb] = __builtin_amdgcn_mfma_f32_16x16x32_bf16(a0, b, acc[0][nb], 0, 0, 0);
            acc[1][nb] = __builtin_amdgcn_mfma_f32_16x16x32_bf16(a1, b, acc[1][nb], 0, 0, 0);
        }
    }

    // C/D layout: col = lane&15, row = (lane>>4)*4 + reg  [m89-verified]
#pragma unroll
    for (int rs = 0; rs < 2; ++rs) {
#pragma unroll
        for (int nb = 0; nb < 8; ++nb) {
            int col = nb * 16 + lrow;
            float bv = bias[col];
#pragma unroll
            for (int r = 0; r < 4; ++r) {
                int node = nodeBase + rs * 16 + lk * 4 + r;
                if (node < N) {
                    float v = fmaxf(acc[rs][nb][r] + bv, 0.f);
                    OUT[(size_t)node * 128 + col] = f2bf(v);
                }
            }
        }
    }
}

// ---------------- P = h @ Wc : one thread per node, Wc LDS-broadcast --------
__global__ __launch_bounds__(256) void k_proj(const unsigned short* __restrict__ hb,
                                              const float* __restrict__ Wc,
                                              float* __restrict__ P, int N) {
    __shared__ float sWc[1536];
    for (int i = threadIdx.x; i < 1536; i += 256) sWc[i] = Wc[i];
    __syncthreads();
    int n = blockIdx.x * 256 + threadIdx.x;
    if (n >= N) return;
    float acc[12];
#pragma unroll
    for (int j = 0; j < 12; ++j) acc[j] = 0.f;
    for (int ci = 0; ci < 16; ++ci) {
        uint4 hv = *(const uint4*)(hb + (size_t)n * 128 + ci * 8);  // 8 bf16
        float hf[8];
        hf[0] = bf16lo(hv.x); hf[1] = bf16hi(hv.x);
        hf[2] = bf16lo(hv.y); hf[3] = bf16hi(hv.y);
        hf[4] = bf16lo(hv.z); hf[5] = bf16hi(hv.z);
        hf[6] = bf16lo(hv.w); hf[7] = bf16hi(hv.w);
#pragma unroll
        for (int i = 0; i < 8; ++i) {
            int c = ci * 8 + i;
#pragma unroll
            for (int j = 0; j < 12; ++j) acc[j] += hf[i] * sWc[c * 12 + j];
        }
    }
#pragma unroll
    for (int j = 0; j < 12; ++j) P[(size_t)n * 12 + j] = acc[j];
}

// ---------------- 6-dim aggregation + finalize ps/pd -----------------------
// 8 lanes per node: lanes 0-2 aggregate t (P cols 3-5) -> ps = u + mean(t);
// lanes 3-5 aggregate w (P cols 9-11) -> pd = v + mean(w).
__global__ __launch_bounds__(256) void k_agg3(const float* __restrict__ P,
                                              const int* __restrict__ eidx,
                                              const int* __restrict__ cursor,
                                              const float* __restrict__ fdeg,
                                              const float* __restrict__ invdeg,
                                              float* __restrict__ ps4,
                                              float* __restrict__ pd4, int N) {
    int g = (blockIdx.x * blockDim.x + threadIdx.x) >> 3;
    int j = threadIdx.x & 7;
    if (g >= N || j >= 6) return;
    int d = (int)fdeg[g];
    int o = cursor[g] - d;
    int col = (j < 3) ? (3 + j) : (6 + j);  // t: 3..5  w: 9..11
    float a = 0.f;
    for (int i = 0; i < d; ++i) {
        int s = eidx[o + i];
        a += P[(size_t)s * 12 + col];
    }
    a *= invdeg[g];
    if (j < 3)
        ps4[(size_t)g * 4 + j] = P[(size_t)g * 12 + j] + a;          // u + mean(t)
    else
        pd4[(size_t)g * 4 + (j - 3)] = P[(size_t)g * 12 + 3 + j] + a; // v + mean(w)
}

__global__ void k_edge(const float4* __restrict__ ps4, const float4* __restrict__ pd4,
                       const int* __restrict__ src, const int* __restrict__ dst,
                       const float* __restrict__ bconst, float* __restrict__ out, int E)
{
    int e = blockIdx.x * blockDim.x + threadIdx.x;
    if (e >= E) return;
    float4 a = ps4[src[e]];
    float4 b = pd4[dst[e]];
    out[(size_t)e * 3 + 0] = a.x + b.x + bconst[0];
    out[(size_t)e * 3 + 1] = a.y + b.y + bconst[1];
    out[(size_t)e * 3 + 2] = a.z + b.z + bconst[2];
}

extern "C" void kernel_launch(void* const* d_in, const int* in_sizes, int n_in,
                              void* d_out, int out_size, void* d_ws, size_t ws_size,
                              hipStream_t stream)
{
    const float* x   = (const float*)d_in[0];
    // d_in[1] = e (edge features) — unused by the reference score
    const int*   src = (const int*)d_in[2];
    const int*   dst = (const int*)d_in[3];
    const float* W1s = (const float*)d_in[4];
    const float* W1n = (const float*)d_in[5];
    const float* b1  = (const float*)d_in[6];
    const float* W2s = (const float*)d_in[7];
    const float* W2n = (const float*)d_in[8];
    const float* b2  = (const float*)d_in[9];
    const float* Wp  = (const float*)d_in[10];
    const float* bp  = (const float*)d_in[11];
    const int N = in_sizes[0] / 128;
    const int E = in_sizes[2];
    float* out = (float*)d_out;

    // ---- workspace carve (256B aligned chunks) ----
    char* wsp = (char*)d_ws;
    auto alloc = [&](size_t bytes) { char* p = wsp; wsp += (bytes + 255) & ~(size_t)255; return p; };
    float* fdeg     = (float*)alloc((size_t)N * 4);
    float* invdeg   = (float*)alloc((size_t)N * 4);
    int*   cursor   = (int*)alloc((size_t)N * 4);
    int*   eidx     = (int*)alloc((size_t)E * 4);
    int*   partials = (int*)alloc(4096);
    unsigned short* xb   = (unsigned short*)alloc((size_t)N * 128 * 2);
    unsigned short* aggb = (unsigned short*)alloc((size_t)N * 128 * 2);
    unsigned short* hb   = (unsigned short*)alloc((size_t)N * 128 * 2);
    unsigned short* Wt1  = (unsigned short*)alloc(256 * 128 * 2);
    float* Wc     = (float*)alloc(1536 * 4);
    float* bconst = (float*)alloc(256);
    float* P      = (float*)alloc((size_t)N * 12 * 4);
    float* ps4    = (float*)alloc((size_t)N * 16);
    float* pd4    = (float*)alloc((size_t)N * 16);

    const int scanBlocks = (N + 1023) / 1024;

    (void)hipMemsetAsync(fdeg, 0, (size_t)N * 4, stream);

    // CSR build
    k_deg<<<(E + 255) / 256, 256, 0, stream>>>(dst, fdeg, E);
    k_scan1<<<scanBlocks, 256, 0, stream>>>(fdeg, cursor, invdeg, partials, N);
    k_scan2<<<1, 64, 0, stream>>>(partials, scanBlocks);
    k_scan3<<<scanBlocks, 256, 0, stream>>>(cursor, partials, N);
    k_fill<<<(E + 255) / 256, 256, 0, stream>>>(src, dst, cursor, eidx, E);

    // feature & weight prep
    k_cvt<<<(N * 32 + 255) / 256, 256, 0, stream>>>(x, xb, N * 32);
    k_prep<<<129, 256, 0, stream>>>(W1s, W1n, Wt1, W2s, W2n, Wp, b2, bp, Wc, bconst);

    // layer 1: agg(x) -> aggb ; h = relu(x@W1s + aggb@W1n + b1)
    k_agg<<<(N + 3) / 4, 256, 0, stream>>>(xb, eidx, cursor, fdeg, invdeg, aggb, N);
    k_gemm_mfma<<<(N + 127) / 128, 256, 0, stream>>>(xb, aggb, Wt1, b1, hb, N);

    // layer 2 (factorized): P = h @ Wc ; ps/pd via 6-dim aggregation
    k_proj<<<(N + 255) / 256, 256, 0, stream>>>(hb, Wc, P, N);
    k_agg3<<<(N * 8 + 255) / 256, 256, 0, stream>>>(P, eidx, cursor, fdeg, invdeg,
                                                    ps4, pd4, N);

    // edge scoring
    k_edge<<<(E + 255) / 256, 256, 0, stream>>>((const float4*)ps4, (const float4*)pd4,
                                                src, dst, bconst, out, E);
}

// Round 6
// 213.674 us; speedup vs baseline: 10.4456x; 1.0872x over previous
//
#include <hip/hip_runtime.h>
#include <hip/hip_bf16.h>

// ---------------------------------------------------------------------------
// GraphSAGE 2-layer (mean agg) + edge MLP predictor.
// Round 6: dispatch-count reduction (13 -> 8).
//  - k_misc fuses {fp32->bf16 cvt, degree atomics, W1 transpose, Wc/bconst}.
//  - k_scan: one kernel; each block recomputes its global carry from fdeg.
//  - P = h @ Wc fused into GEMM epilogue; layer-1 output h never materialized.
// score[e] = ps[src] + pd[dst] + bconst,
//   ps[n] = P[n].u + mean_in(P[src].t),  pd[n] = P[n].v + mean_in(P[src].w)
// ---------------------------------------------------------------------------

typedef __attribute__((ext_vector_type(8))) short bf16x8;
typedef __attribute__((ext_vector_type(4))) float f32x4;

static __device__ __forceinline__ float bf16lo(unsigned u) {
    return __uint_as_float(u << 16);
}
static __device__ __forceinline__ float bf16hi(unsigned u) {
    return __uint_as_float(u & 0xffff0000u);
}
static __device__ __forceinline__ unsigned short f2bf(float f) {
    unsigned u = __float_as_uint(f);
    unsigned r = 0x7fffu + ((u >> 16) & 1u);  // round to nearest even
    return (unsigned short)((u + r) >> 16);
}
static __device__ __forceinline__ unsigned pack_bf162(float a, float b) {
    return (unsigned)f2bf(a) | ((unsigned)f2bf(b) << 16);
}

// ---------------- fused misc: cvt | degree | Wt1 prep | Wc prep -------------
__global__ __launch_bounds__(256) void k_misc(
    const float* __restrict__ x, unsigned short* __restrict__ xb,
    const int* __restrict__ dst, float* __restrict__ fdeg,
    const float* __restrict__ W1s, const float* __restrict__ W1n,
    unsigned short* __restrict__ Wt1,
    const float* __restrict__ W2s, const float* __restrict__ W2n,
    const float* __restrict__ Wp, const float* __restrict__ b2,
    const float* __restrict__ bp, float* __restrict__ Wc,
    float* __restrict__ bconst, int N, int E)
{
    const int nCvt = (N * 32 + 255) / 256;
    const int nDeg = (E + 255) / 256;
    const int b = blockIdx.x;
    const int t = threadIdx.x;

    if (b < nCvt) {
        int i = b * 256 + t;
        if (i < N * 32) {
            float4 v = ((const float4*)x)[i];
            uint2 o;
            o.x = pack_bf162(v.x, v.y);
            o.y = pack_bf162(v.z, v.w);
            *(uint2*)(xb + (size_t)i * 4) = o;
        }
    } else if (b < nCvt + nDeg) {
        int e = (b - nCvt) * 256 + t;
        if (e < E) atomicAdd(&fdeg[dst[e]], 1.0f);
    } else if (b < nCvt + nDeg + 128) {
        int id = (b - nCvt - nDeg) * 256 + t;  // 32768 total
        int k = id >> 7, n = id & 127;
        float v = (k < 128) ? W1s[k * 128 + n] : W1n[(k - 128) * 128 + n];
        Wt1[n * 256 + k] = f2bf(v);
    } else {
        // Wc[c][j]: j 0-2 u=W2s@Wp_top, 3-5 t=W2n@Wp_top,
        //             6-8 v=W2s@Wp_bot, 9-11 w=W2n@Wp_bot; bconst
        for (int id = t; id < 1539; id += 256) {
            if (id < 1536) {
                int c = id / 12, j = id % 12;
                int q = j / 3, jj = j % 3;
                const float* W2 = (q == 0 || q == 2) ? W2s : W2n;
                int wpoff = (q < 2) ? 0 : 128;
                float s = 0.f;
                for (int m = 0; m < 128; ++m)
                    s += W2[c * 128 + m] * Wp[(wpoff + m) * 3 + jj];
                Wc[c * 12 + j] = s;
            } else {
                int jj = id - 1536;
                float s = bp[jj];
                for (int m = 0; m < 128; ++m)
                    s += b2[m] * (Wp[m * 3 + jj] + Wp[(128 + m) * 3 + jj]);
                bconst[jj] = s;
            }
        }
    }
}

// ---------------- one-kernel exclusive scan ---------------------------------
// Each block owns a 1024-tile; recomputes its global carry from fdeg directly
// (deg values are small ints in float -> exact). No cross-block comm.
__global__ __launch_bounds__(256) void k_scan(const float* __restrict__ fdeg,
                                              int* __restrict__ cursor,
                                              float* __restrict__ invdeg, int N) {
    __shared__ int sred[4];
    __shared__ int wsum[4];
    const int t = threadIdx.x;
    const int lane = t & 63, wv = t >> 6;
    const int base = blockIdx.x * 1024;

    // carry = sum fdeg[0..base)
    int c = 0;
    for (int i = t * 4; i < base; i += 1024) {
        float4 v = *(const float4*)&fdeg[i];
        c += (int)v.x + (int)v.y + (int)v.z + (int)v.w;
    }
#pragma unroll
    for (int off = 32; off; off >>= 1) c += __shfl_xor(c, off, 64);
    if (lane == 0) sred[wv] = c;
    __syncthreads();
    const int carry = sred[0] + sred[1] + sred[2] + sred[3];

    // tile scan
    int d[4];
#pragma unroll
    for (int j = 0; j < 4; ++j) {
        int i = base + t * 4 + j;
        float f = (i < N) ? fdeg[i] : 0.f;
        d[j] = (int)f;
        if (i < N) invdeg[i] = 1.0f / fmaxf(f, 1.0f);
    }
    int s = d[0] + d[1] + d[2] + d[3];
    int incl = s;
#pragma unroll
    for (int off = 1; off < 64; off <<= 1) {
        int u = __shfl_up(incl, off, 64);
        if (lane >= off) incl += u;
    }
    if (lane == 63) wsum[wv] = incl;
    __syncthreads();
    int woff = carry;
#pragma unroll
    for (int w = 0; w < 4; ++w)
        if (w < wv) woff += wsum[w];
    int p = (incl - s) + woff;
#pragma unroll
    for (int j = 0; j < 4; ++j) {
        int i = base + t * 4 + j;
        if (i < N) cursor[i] = p;
        p += d[j];
    }
}

// ---------------- CSR fill ----------------
__global__ void k_fill(const int* __restrict__ src, const int* __restrict__ dst,
                       int* __restrict__ cursor, int* __restrict__ eidx, int E) {
    int e = blockIdx.x * blockDim.x + threadIdx.x;
    if (e < E) {
        int p = atomicAdd(&cursor[dst[e]], 1);
        eidx[p] = src[e];
    }
}

// ---------------- mean aggregation (bf16 gather, fp32 acc, bf16 out) -------
// One wave per dst node; half-wave per edge (32 lanes x 8B = 256B row).
__global__ __launch_bounds__(256) void k_agg(const unsigned short* __restrict__ Xb,
                                             const int* __restrict__ eidx,
                                             const int* __restrict__ cursor,
                                             const float* __restrict__ fdeg,
                                             const float* __restrict__ invdeg,
                                             unsigned short* __restrict__ OUT, int N) {
    int w = (blockIdx.x * blockDim.x + threadIdx.x) >> 6;
    int lane = threadIdx.x & 63;
    if (w >= N) return;
    int d = (int)fdeg[w];
    int o = cursor[w] - d;  // cursor holds end offset after k_fill
    int half = lane >> 5, q = lane & 31;
    float4 acc = make_float4(0.f, 0.f, 0.f, 0.f);
    for (int j = 0; j < d; j += 2) {
        int je = j + half;
        if (je < d) {
            int s = eidx[o + je];
            uint2 v = *(const uint2*)(Xb + (size_t)s * 128 + q * 4);
            acc.x += bf16lo(v.x);
            acc.y += bf16hi(v.x);
            acc.z += bf16lo(v.y);
            acc.w += bf16hi(v.y);
        }
    }
    acc.x += __shfl_xor(acc.x, 32, 64);
    acc.y += __shfl_xor(acc.y, 32, 64);
    acc.z += __shfl_xor(acc.z, 32, 64);
    acc.w += __shfl_xor(acc.w, 32, 64);
    if (half == 0) {
        float sc = invdeg[w];
        uint2 ov;
        ov.x = pack_bf162(acc.x * sc, acc.y * sc);
        ov.y = pack_bf162(acc.z * sc, acc.w * sc);
        *(uint2*)(OUT + (size_t)w * 128 + q * 4) = ov;
    }
}

// ---------------- MFMA GEMM + fused projection ------------------------------
// h[n] = relu([xb|aggb][n][256] @ Wt1^T + b1)  (registers only, never stored)
// P[n][12] = h[n] @ Wc   (12 dots via 16-lane shfl allreduce)
// Block: 256 thr (4 waves), 128 nodes. Wt1 staged in LDS, XOR-swizzled (G4).
__global__ __launch_bounds__(256) void k_gemm_proj(
    const unsigned short* __restrict__ A0, const unsigned short* __restrict__ A1,
    const unsigned short* __restrict__ Wt, const float* __restrict__ bias,
    const float* __restrict__ Wc, float* __restrict__ P, int N)
{
    __shared__ __align__(16) char sW[65536];  // Wt swizzled: 128 rows x 512B
    __shared__ float sWc[1536];
    const int t = threadIdx.x;

#pragma unroll
    for (int i = 0; i < 16; ++i) {
        int o = (i * 256 + t) * 16;
        int n = o >> 9;
        int c = o & 511;
        int sw = (n << 9) | (c ^ ((n & 7) << 4));
        *(float4*)&sW[sw] = *(const float4*)((const char*)Wt + o);
    }
    for (int i = t; i < 1536; i += 256) sWc[i] = Wc[i];

    const int wave = t >> 6, lane = t & 63;
    const int nodeBase = blockIdx.x * 128 + wave * 32;
    const int lrow = lane & 15, lk = lane >> 4;

    f32x4 acc[2][8];
#pragma unroll
    for (int rs = 0; rs < 2; ++rs)
#pragma unroll
        for (int nb = 0; nb < 8; ++nb) acc[rs][nb] = (f32x4){0.f, 0.f, 0.f, 0.f};

    __syncthreads();

    const int r0 = nodeBase + lrow, r1 = nodeBase + 16 + lrow;
    for (int ks = 0; ks < 8; ++ks) {
        const unsigned short* Asrc = (ks < 4) ? A0 : A1;
        const int kk = (ks & 3) * 32 + lk * 8;
        bf16x8 a0 = {}, a1 = {};
        if (r0 < N) a0 = *(const bf16x8*)(Asrc + (size_t)r0 * 128 + kk);
        if (r1 < N) a1 = *(const bf16x8*)(Asrc + (size_t)r1 * 128 + kk);
        const int cbase = ks * 64 + lk * 16;  // byte col within 512B row
#pragma unroll
        for (int nb = 0; nb < 8; ++nb) {
            int n = nb * 16 + lrow;
            int sw = (n << 9) | (cbase ^ ((n & 7) << 4));
            bf16x8 b = *(const bf16x8*)&sW[sw];
            acc[0][nb] = __builtin_amdgcn_mfma_f32_16x16x32_bf16(a0, b, acc[0][nb], 0, 0, 0);
            acc[1][nb] = __builtin_amdgcn_mfma_f32_16x16x32_bf16(a1, b, acc[1][nb], 0, 0, 0);
        }
    }

    // Epilogue: C/D layout col = lane&15, row = (lane>>4)*4 + reg [m89].
    // h(node, col=nb*16+lrow) = relu(acc + bias); P[node][j] = sum_col h*Wc.
#pragma unroll
    for (int rs = 0; rs < 2; ++rs) {
        float hval[8][4];
#pragma unroll
        for (int nb = 0; nb < 8; ++nb) {
            float bv = bias[nb * 16 + lrow];
#pragma unroll
            for (int r = 0; r < 4; ++r)
                hval[nb][r] = fmaxf(acc[rs][nb][r] + bv, 0.f);
        }
#pragma unroll
        for (int r = 0; r < 4; ++r) {
            float pj[12];
#pragma unroll
            for (int j = 0; j < 12; ++j) pj[j] = 0.f;
#pragma unroll
            for (int nb = 0; nb < 8; ++nb) {
                float hv = hval[nb][r];
                const float* wrow = &sWc[(nb * 16 + lrow) * 12];
#pragma unroll
                for (int j = 0; j < 12; ++j) pj[j] += hv * wrow[j];
            }
            // allreduce over the 16 lanes sharing lk (lrow dimension)
#pragma unroll
            for (int off = 8; off; off >>= 1) {
#pragma unroll
                for (int j = 0; j < 12; ++j) pj[j] += __shfl_xor(pj[j], off, 64);
            }
            int node = nodeBase + rs * 16 + lk * 4 + r;
            if (lrow == 0 && node < N) {
                float* prow = &P[(size_t)node * 12];
                *(float4*)(prow + 0) = make_float4(pj[0], pj[1], pj[2], pj[3]);
                *(float4*)(prow + 4) = make_float4(pj[4], pj[5], pj[6], pj[7]);
                *(float4*)(prow + 8) = make_float4(pj[8], pj[9], pj[10], pj[11]);
            }
        }
    }
}

// ---------------- 6-dim aggregation + finalize ps/pd -----------------------
// 8 lanes per node: lanes 0-2 aggregate t (P cols 3-5) -> ps = u + mean(t);
// lanes 3-5 aggregate w (P cols 9-11) -> pd = v + mean(w).
__global__ __launch_bounds__(256) void k_agg3(const float* __restrict__ P,
                                              const int* __restrict__ eidx,
                                              const int* __restrict__ cursor,
                                              const float* __restrict__ fdeg,
                                              const float* __restrict__ invdeg,
                                              float* __restrict__ ps4,
                                              float* __restrict__ pd4, int N) {
    int g = (blockIdx.x * blockDim.x + threadIdx.x) >> 3;
    int j = threadIdx.x & 7;
    if (g >= N || j >= 6) return;
    int d = (int)fdeg[g];
    int o = cursor[g] - d;
    int col = (j < 3) ? (3 + j) : (6 + j);  // t: 3..5  w: 9..11
    float a = 0.f;
    for (int i = 0; i < d; ++i) {
        int s = eidx[o + i];
        a += P[(size_t)s * 12 + col];
    }
    a *= invdeg[g];
    if (j < 3)
        ps4[(size_t)g * 4 + j] = P[(size_t)g * 12 + j] + a;           // u + mean(t)
    else
        pd4[(size_t)g * 4 + (j - 3)] = P[(size_t)g * 12 + 3 + j] + a; // v + mean(w)
}

__global__ void k_edge(const float4* __restrict__ ps4, const float4* __restrict__ pd4,
                       const int* __restrict__ src, const int* __restrict__ dst,
                       const float* __restrict__ bconst, float* __restrict__ out, int E)
{
    int e = blockIdx.x * blockDim.x + threadIdx.x;
    if (e >= E) return;
    float4 a = ps4[src[e]];
    float4 b = pd4[dst[e]];
    out[(size_t)e * 3 + 0] = a.x + b.x + bconst[0];
    out[(size_t)e * 3 + 1] = a.y + b.y + bconst[1];
    out[(size_t)e * 3 + 2] = a.z + b.z + bconst[2];
}

extern "C" void kernel_launch(void* const* d_in, const int* in_sizes, int n_in,
                              void* d_out, int out_size, void* d_ws, size_t ws_size,
                              hipStream_t stream)
{
    const float* x   = (const float*)d_in[0];
    // d_in[1] = e (edge features) — unused by the reference score
    const int*   src = (const int*)d_in[2];
    const int*   dst = (const int*)d_in[3];
    const float* W1s = (const float*)d_in[4];
    const float* W1n = (const float*)d_in[5];
    const float* b1  = (const float*)d_in[6];
    const float* W2s = (const float*)d_in[7];
    const float* W2n = (const float*)d_in[8];
    const float* b2  = (const float*)d_in[9];
    const float* Wp  = (const float*)d_in[10];
    const float* bp  = (const float*)d_in[11];
    const int N = in_sizes[0] / 128;
    const int E = in_sizes[2];
    float* out = (float*)d_out;

    // ---- workspace carve (256B aligned chunks) ----
    char* wsp = (char*)d_ws;
    auto alloc = [&](size_t bytes) { char* p = wsp; wsp += (bytes + 255) & ~(size_t)255; return p; };
    float* fdeg     = (float*)alloc((size_t)N * 4);
    float* invdeg   = (float*)alloc((size_t)N * 4);
    int*   cursor   = (int*)alloc((size_t)N * 4);
    int*   eidx     = (int*)alloc((size_t)E * 4);
    unsigned short* xb   = (unsigned short*)alloc((size_t)N * 128 * 2);
    unsigned short* aggb = (unsigned short*)alloc((size_t)N * 128 * 2);
    unsigned short* Wt1  = (unsigned short*)alloc(256 * 128 * 2);
    float* Wc     = (float*)alloc(1536 * 4);
    float* bconst = (float*)alloc(256);
    float* P      = (float*)alloc((size_t)N * 12 * 4);
    float* ps4    = (float*)alloc((size_t)N * 16);
    float* pd4    = (float*)alloc((size_t)N * 16);

    (void)hipMemsetAsync(fdeg, 0, (size_t)N * 4, stream);

    // fused cvt | degree | weight prep
    const int nCvt = (N * 32 + 255) / 256;
    const int nDeg = (E + 255) / 256;
    k_misc<<<nCvt + nDeg + 129, 256, 0, stream>>>(x, xb, dst, fdeg,
                                                  W1s, W1n, Wt1,
                                                  W2s, W2n, Wp, b2, bp, Wc, bconst,
                                                  N, E);

    // CSR: scan (self-carry) + fill
    k_scan<<<(N + 1023) / 1024, 256, 0, stream>>>(fdeg, cursor, invdeg, N);
    k_fill<<<(E + 255) / 256, 256, 0, stream>>>(src, dst, cursor, eidx, E);

    // layer 1 aggregation + fused GEMM->P (h never materialized)
    k_agg<<<(N + 3) / 4, 256, 0, stream>>>(xb, eidx, cursor, fdeg, invdeg, aggb, N);
    k_gemm_proj<<<(N + 127) / 128, 256, 0, stream>>>(xb, aggb, Wt1, b1, Wc, P, N);

    // layer 2 (factorized): 6-dim aggregation -> ps/pd
    k_agg3<<<(N * 8 + 255) / 256, 256, 0, stream>>>(P, eidx, cursor, fdeg, invdeg,
                                                    ps4, pd4, N);

    // edge scoring
    k_edge<<<(E + 255) / 256, 256, 0, stream>>>((const float4*)ps4, (const float4*)pd4,
                                                src, dst, bconst, out, E);
}

// Round 7
// 206.481 us; speedup vs baseline: 10.8096x; 1.0348x over previous
//
#include <hip/hip_runtime.h>
#include <hip/hip_bf16.h>

// ---------------------------------------------------------------------------
// GraphSAGE 2-layer (mean agg) + edge MLP predictor.
// Round 7: aggregation fused into the MFMA GEMM as register-space gather
// (aggb buffer and k_agg dispatch eliminated); P padded to 16 floats/row.
// score[e] = ps[src] + pd[dst] + bconst,
//   ps[n] = P[n].u + mean_in(P[src].t),  pd[n] = P[n].v + mean_in(P[src].w)
// ---------------------------------------------------------------------------

typedef __attribute__((ext_vector_type(8))) short bf16x8;
typedef __attribute__((ext_vector_type(4))) float f32x4;

static __device__ __forceinline__ float bf16lo(unsigned u) {
    return __uint_as_float(u << 16);
}
static __device__ __forceinline__ float bf16hi(unsigned u) {
    return __uint_as_float(u & 0xffff0000u);
}
static __device__ __forceinline__ unsigned short f2bf(float f) {
    unsigned u = __float_as_uint(f);
    unsigned r = 0x7fffu + ((u >> 16) & 1u);  // round to nearest even
    return (unsigned short)((u + r) >> 16);
}
static __device__ __forceinline__ unsigned pack_bf162(float a, float b) {
    return (unsigned)f2bf(a) | ((unsigned)f2bf(b) << 16);
}

// ---------------- fused misc: cvt | degree | Wt1 prep | Wc prep -------------
__global__ __launch_bounds__(256) void k_misc(
    const float* __restrict__ x, unsigned short* __restrict__ xb,
    const int* __restrict__ dst, float* __restrict__ fdeg,
    const float* __restrict__ W1s, const float* __restrict__ W1n,
    unsigned short* __restrict__ Wt1,
    const float* __restrict__ W2s, const float* __restrict__ W2n,
    const float* __restrict__ Wp, const float* __restrict__ b2,
    const float* __restrict__ bp, float* __restrict__ Wc,
    float* __restrict__ bconst, int N, int E)
{
    const int nCvt = (N * 32 + 255) / 256;
    const int nDeg = (E + 255) / 256;
    const int b = blockIdx.x;
    const int t = threadIdx.x;

    if (b < nCvt) {
        int i = b * 256 + t;
        if (i < N * 32) {
            float4 v = ((const float4*)x)[i];
            uint2 o;
            o.x = pack_bf162(v.x, v.y);
            o.y = pack_bf162(v.z, v.w);
            *(uint2*)(xb + (size_t)i * 4) = o;
        }
    } else if (b < nCvt + nDeg) {
        int e = (b - nCvt) * 256 + t;
        if (e < E) atomicAdd(&fdeg[dst[e]], 1.0f);
    } else if (b < nCvt + nDeg + 128) {
        int id = (b - nCvt - nDeg) * 256 + t;  // 32768 total
        int k = id >> 7, n = id & 127;
        float v = (k < 128) ? W1s[k * 128 + n] : W1n[(k - 128) * 128 + n];
        Wt1[n * 256 + k] = f2bf(v);
    } else {
        // Wc[c][j]: j 0-2 u=W2s@Wp_top, 3-5 t=W2n@Wp_top,
        //             6-8 v=W2s@Wp_bot, 9-11 w=W2n@Wp_bot; bconst
        for (int id = t; id < 1539; id += 256) {
            if (id < 1536) {
                int c = id / 12, j = id % 12;
                int q = j / 3, jj = j % 3;
                const float* W2 = (q == 0 || q == 2) ? W2s : W2n;
                int wpoff = (q < 2) ? 0 : 128;
                float s = 0.f;
                for (int m = 0; m < 128; ++m)
                    s += W2[c * 128 + m] * Wp[(wpoff + m) * 3 + jj];
                Wc[c * 12 + j] = s;
            } else {
                int jj = id - 1536;
                float s = bp[jj];
                for (int m = 0; m < 128; ++m)
                    s += b2[m] * (Wp[m * 3 + jj] + Wp[(128 + m) * 3 + jj]);
                bconst[jj] = s;
            }
        }
    }
}

// ---------------- one-kernel exclusive scan ---------------------------------
__global__ __launch_bounds__(256) void k_scan(const float* __restrict__ fdeg,
                                              int* __restrict__ cursor,
                                              float* __restrict__ invdeg, int N) {
    __shared__ int sred[4];
    __shared__ int wsum[4];
    const int t = threadIdx.x;
    const int lane = t & 63, wv = t >> 6;
    const int base = blockIdx.x * 1024;

    // carry = sum fdeg[0..base)
    int c = 0;
    for (int i = t * 4; i < base; i += 1024) {
        float4 v = *(const float4*)&fdeg[i];
        c += (int)v.x + (int)v.y + (int)v.z + (int)v.w;
    }
#pragma unroll
    for (int off = 32; off; off >>= 1) c += __shfl_xor(c, off, 64);
    if (lane == 0) sred[wv] = c;
    __syncthreads();
    const int carry = sred[0] + sred[1] + sred[2] + sred[3];

    int d[4];
#pragma unroll
    for (int j = 0; j < 4; ++j) {
        int i = base + t * 4 + j;
        float f = (i < N) ? fdeg[i] : 0.f;
        d[j] = (int)f;
        if (i < N) invdeg[i] = 1.0f / fmaxf(f, 1.0f);
    }
    int s = d[0] + d[1] + d[2] + d[3];
    int incl = s;
#pragma unroll
    for (int off = 1; off < 64; off <<= 1) {
        int u = __shfl_up(incl, off, 64);
        if (lane >= off) incl += u;
    }
    if (lane == 63) wsum[wv] = incl;
    __syncthreads();
    int woff = carry;
#pragma unroll
    for (int w = 0; w < 4; ++w)
        if (w < wv) woff += wsum[w];
    int p = (incl - s) + woff;
#pragma unroll
    for (int j = 0; j < 4; ++j) {
        int i = base + t * 4 + j;
        if (i < N) cursor[i] = p;
        p += d[j];
    }
}

// ---------------- CSR fill ----------------
__global__ void k_fill(const int* __restrict__ src, const int* __restrict__ dst,
                       int* __restrict__ cursor, int* __restrict__ eidx, int E) {
    int e = blockIdx.x * blockDim.x + threadIdx.x;
    if (e < E) {
        int p = atomicAdd(&cursor[dst[e]], 1);
        eidx[p] = src[e];
    }
}

// ---------------- fused gather-aggregate + MFMA GEMM + projection -----------
// Per wave: 32 nodes (r0=nodeBase+lrow, r1=r0+16). Lane (lrow,lk) aggregates
// agg dims {ksb*32+lk*8+0..7} of its 2 nodes in fp32 regs (gathered from xb),
// packs to bf16 MFMA A-fragments for ks=4..7. ks=0..3 A-fragments read xb.
// h = relu(...) lives in registers; P[n][12] = h @ Wc via 16-lane allreduce.
__global__ __launch_bounds__(256) void k_gemm_fused(
    const unsigned short* __restrict__ xb,
    const int* __restrict__ eidx, const int* __restrict__ cursor,
    const float* __restrict__ fdeg, const float* __restrict__ invdeg,
    const unsigned short* __restrict__ Wt, const float* __restrict__ bias,
    const float* __restrict__ Wc, float* __restrict__ P, int N)
{
    __shared__ __align__(16) char sW[65536];  // Wt swizzled: 128 rows x 512B
    __shared__ float sWc[1536];
    const int t = threadIdx.x;

#pragma unroll
    for (int i = 0; i < 16; ++i) {
        int o = (i * 256 + t) * 16;
        int n = o >> 9;
        int c = o & 511;
        int sw = (n << 9) | (c ^ ((n & 7) << 4));
        *(float4*)&sW[sw] = *(const float4*)((const char*)Wt + o);
    }
    for (int i = t; i < 1536; i += 256) sWc[i] = Wc[i];

    const int wave = t >> 6, lane = t & 63;
    const int nodeBase = blockIdx.x * 128 + wave * 32;
    const int lrow = lane & 15, lk = lane >> 4;
    const int r0 = nodeBase + lrow, r1 = nodeBase + 16 + lrow;

    union { bf16x8 v; unsigned u[4]; } afrag0[4], afrag1[4];

    // ---- register-space aggregation for r0, r1 ----
    {
        float agg[4][8];
#pragma unroll
        for (int ksb = 0; ksb < 4; ++ksb)
#pragma unroll
            for (int i = 0; i < 8; ++i) agg[ksb][i] = 0.f;
        if (r0 < N) {
            int d = (int)fdeg[r0], o = cursor[r0] - d;
            for (int j = 0; j < d; ++j) {
                int s = eidx[o + j];
                const unsigned short* row = xb + (size_t)s * 128 + lk * 8;
#pragma unroll
                for (int ksb = 0; ksb < 4; ++ksb) {
                    uint4 v = *(const uint4*)(row + ksb * 32);
                    agg[ksb][0] += bf16lo(v.x); agg[ksb][1] += bf16hi(v.x);
                    agg[ksb][2] += bf16lo(v.y); agg[ksb][3] += bf16hi(v.y);
                    agg[ksb][4] += bf16lo(v.z); agg[ksb][5] += bf16hi(v.z);
                    agg[ksb][6] += bf16lo(v.w); agg[ksb][7] += bf16hi(v.w);
                }
            }
            float sc = invdeg[r0];
#pragma unroll
            for (int ksb = 0; ksb < 4; ++ksb)
#pragma unroll
                for (int i = 0; i < 4; ++i)
                    afrag0[ksb].u[i] = pack_bf162(agg[ksb][2 * i] * sc,
                                                  agg[ksb][2 * i + 1] * sc);
        } else {
#pragma unroll
            for (int ksb = 0; ksb < 4; ++ksb)
#pragma unroll
                for (int i = 0; i < 4; ++i) afrag0[ksb].u[i] = 0u;
        }
    }
    {
        float agg[4][8];
#pragma unroll
        for (int ksb = 0; ksb < 4; ++ksb)
#pragma unroll
            for (int i = 0; i < 8; ++i) agg[ksb][i] = 0.f;
        if (r1 < N) {
            int d = (int)fdeg[r1], o = cursor[r1] - d;
            for (int j = 0; j < d; ++j) {
                int s = eidx[o + j];
                const unsigned short* row = xb + (size_t)s * 128 + lk * 8;
#pragma unroll
                for (int ksb = 0; ksb < 4; ++ksb) {
                    uint4 v = *(const uint4*)(row + ksb * 32);
                    agg[ksb][0] += bf16lo(v.x); agg[ksb][1] += bf16hi(v.x);
                    agg[ksb][2] += bf16lo(v.y); agg[ksb][3] += bf16hi(v.y);
                    agg[ksb][4] += bf16lo(v.z); agg[ksb][5] += bf16hi(v.z);
                    agg[ksb][6] += bf16lo(v.w); agg[ksb][7] += bf16hi(v.w);
                }
            }
            float sc = invdeg[r1];
#pragma unroll
            for (int ksb = 0; ksb < 4; ++ksb)
#pragma unroll
                for (int i = 0; i < 4; ++i)
                    afrag1[ksb].u[i] = pack_bf162(agg[ksb][2 * i] * sc,
                                                  agg[ksb][2 * i + 1] * sc);
        } else {
#pragma unroll
            for (int ksb = 0; ksb < 4; ++ksb)
#pragma unroll
                for (int i = 0; i < 4; ++i) afrag1[ksb].u[i] = 0u;
        }
    }

    f32x4 acc[2][8];
#pragma unroll
    for (int rs = 0; rs < 2; ++rs)
#pragma unroll
        for (int nb = 0; nb < 8; ++nb) acc[rs][nb] = (f32x4){0.f, 0.f, 0.f, 0.f};

    __syncthreads();

    for (int ks = 0; ks < 8; ++ks) {
        bf16x8 a0, a1;
        if (ks < 4) {
            const int kk = ks * 32 + lk * 8;
            a0 = (bf16x8){};
            a1 = (bf16x8){};
            if (r0 < N) a0 = *(const bf16x8*)(xb + (size_t)r0 * 128 + kk);
            if (r1 < N) a1 = *(const bf16x8*)(xb + (size_t)r1 * 128 + kk);
        } else {
            a0 = afrag0[ks - 4].v;
            a1 = afrag1[ks - 4].v;
        }
        const int cbase = ks * 64 + lk * 16;  // byte col within 512B row
#pragma unroll
        for (int nb = 0; nb < 8; ++nb) {
            int n = nb * 16 + lrow;
            int sw = (n << 9) | (cbase ^ ((n & 7) << 4));
            bf16x8 b = *(const bf16x8*)&sW[sw];
            acc[0][nb] = __builtin_amdgcn_mfma_f32_16x16x32_bf16(a0, b, acc[0][nb], 0, 0, 0);
            acc[1][nb] = __builtin_amdgcn_mfma_f32_16x16x32_bf16(a1, b, acc[1][nb], 0, 0, 0);
        }
    }

    // Epilogue: C/D layout col = lane&15, row = (lane>>4)*4 + reg [m89].
    // h(node, col=nb*16+lrow) = relu(acc + bias); P[node][j] = sum_col h*Wc.
#pragma unroll
    for (int rs = 0; rs < 2; ++rs) {
        float hval[8][4];
#pragma unroll
        for (int nb = 0; nb < 8; ++nb) {
            float bv = bias[nb * 16 + lrow];
#pragma unroll
            for (int r = 0; r < 4; ++r)
                hval[nb][r] = fmaxf(acc[rs][nb][r] + bv, 0.f);
        }
#pragma unroll
        for (int r = 0; r < 4; ++r) {
            float pj[12];
#pragma unroll
            for (int j = 0; j < 12; ++j) pj[j] = 0.f;
#pragma unroll
            for (int nb = 0; nb < 8; ++nb) {
                float hv = hval[nb][r];
                const float* wrow = &sWc[(nb * 16 + lrow) * 12];
#pragma unroll
                for (int j = 0; j < 12; ++j) pj[j] += hv * wrow[j];
            }
#pragma unroll
            for (int off = 8; off; off >>= 1) {
#pragma unroll
                for (int j = 0; j < 12; ++j) pj[j] += __shfl_xor(pj[j], off, 64);
            }
            int node = nodeBase + rs * 16 + lk * 4 + r;
            if (lrow == 0 && node < N) {
                float* prow = &P[(size_t)node * 16];   // padded to 64B rows
                *(float4*)(prow + 0) = make_float4(pj[0], pj[1], pj[2], pj[3]);
                *(float4*)(prow + 4) = make_float4(pj[4], pj[5], pj[6], pj[7]);
                *(float4*)(prow + 8) = make_float4(pj[8], pj[9], pj[10], pj[11]);
            }
        }
    }
}

// ---------------- 6-dim aggregation + finalize ps/pd -----------------------
// 8 lanes per node: lanes 0-2 aggregate t (P cols 3-5) -> ps = u + mean(t);
// lanes 3-5 aggregate w (P cols 9-11) -> pd = v + mean(w).
__global__ __launch_bounds__(256) void k_agg3(const float* __restrict__ P,
                                              const int* __restrict__ eidx,
                                              const int* __restrict__ cursor,
                                              const float* __restrict__ fdeg,
                                              const float* __restrict__ invdeg,
                                              float* __restrict__ ps4,
                                              float* __restrict__ pd4, int N) {
    int g = (blockIdx.x * blockDim.x + threadIdx.x) >> 3;
    int j = threadIdx.x & 7;
    if (g >= N || j >= 6) return;
    int d = (int)fdeg[g];
    int o = cursor[g] - d;
    int col = (j < 3) ? (3 + j) : (6 + j);  // t: 3..5  w: 9..11
    float a = 0.f;
    for (int i = 0; i < d; ++i) {
        int s = eidx[o + i];
        a += P[(size_t)s * 16 + col];
    }
    a *= invdeg[g];
    if (j < 3)
        ps4[(size_t)g * 4 + j] = P[(size_t)g * 16 + j] + a;           // u + mean(t)
    else
        pd4[(size_t)g * 4 + (j - 3)] = P[(size_t)g * 16 + 3 + j] + a; // v + mean(w)
}

__global__ void k_edge(const float4* __restrict__ ps4, const float4* __restrict__ pd4,
                       const int* __restrict__ src, const int* __restrict__ dst,
                       const float* __restrict__ bconst, float* __restrict__ out, int E)
{
    int e = blockIdx.x * blockDim.x + threadIdx.x;
    if (e >= E) return;
    float4 a = ps4[src[e]];
    float4 b = pd4[dst[e]];
    out[(size_t)e * 3 + 0] = a.x + b.x + bconst[0];
    out[(size_t)e * 3 + 1] = a.y + b.y + bconst[1];
    out[(size_t)e * 3 + 2] = a.z + b.z + bconst[2];
}

extern "C" void kernel_launch(void* const* d_in, const int* in_sizes, int n_in,
                              void* d_out, int out_size, void* d_ws, size_t ws_size,
                              hipStream_t stream)
{
    const float* x   = (const float*)d_in[0];
    // d_in[1] = e (edge features) — unused by the reference score
    const int*   src = (const int*)d_in[2];
    const int*   dst = (const int*)d_in[3];
    const float* W1s = (const float*)d_in[4];
    const float* W1n = (const float*)d_in[5];
    const float* b1  = (const float*)d_in[6];
    const float* W2s = (const float*)d_in[7];
    const float* W2n = (const float*)d_in[8];
    const float* b2  = (const float*)d_in[9];
    const float* Wp  = (const float*)d_in[10];
    const float* bp  = (const float*)d_in[11];
    const int N = in_sizes[0] / 128;
    const int E = in_sizes[2];
    float* out = (float*)d_out;

    // ---- workspace carve (256B aligned chunks) ----
    char* wsp = (char*)d_ws;
    auto alloc = [&](size_t bytes) { char* p = wsp; wsp += (bytes + 255) & ~(size_t)255; return p; };
    float* fdeg     = (float*)alloc((size_t)N * 4);
    float* invdeg   = (float*)alloc((size_t)N * 4);
    int*   cursor   = (int*)alloc((size_t)N * 4);
    int*   eidx     = (int*)alloc((size_t)E * 4);
    unsigned short* xb  = (unsigned short*)alloc((size_t)N * 128 * 2);
    unsigned short* Wt1 = (unsigned short*)alloc(256 * 128 * 2);
    float* Wc     = (float*)alloc(1536 * 4);
    float* bconst = (float*)alloc(256);
    float* P      = (float*)alloc((size_t)N * 16 * 4);   // padded 64B rows
    float* ps4    = (float*)alloc((size_t)N * 16);
    float* pd4    = (float*)alloc((size_t)N * 16);

    (void)hipMemsetAsync(fdeg, 0, (size_t)N * 4, stream);

    // fused cvt | degree | weight prep
    const int nCvt = (N * 32 + 255) / 256;
    const int nDeg = (E + 255) / 256;
    k_misc<<<nCvt + nDeg + 129, 256, 0, stream>>>(x, xb, dst, fdeg,
                                                  W1s, W1n, Wt1,
                                                  W2s, W2n, Wp, b2, bp, Wc, bconst,
                                                  N, E);

    // CSR: scan (self-carry) + fill
    k_scan<<<(N + 1023) / 1024, 256, 0, stream>>>(fdeg, cursor, invdeg, N);
    k_fill<<<(E + 255) / 256, 256, 0, stream>>>(src, dst, cursor, eidx, E);

    // layer 1 + projection, fully fused (agg in registers, h never stored)
    k_gemm_fused<<<(N + 127) / 128, 256, 0, stream>>>(xb, eidx, cursor, fdeg, invdeg,
                                                      Wt1, b1, Wc, P, N);

    // layer 2 (factorized): 6-dim aggregation -> ps/pd
    k_agg3<<<(N * 8 + 255) / 256, 256, 0, stream>>>(P, eidx, cursor, fdeg, invdeg,
                                                    ps4, pd4, N);

    // edge scoring
    k_edge<<<(E + 255) / 256, 256, 0, stream>>>((const float4*)ps4, (const float4*)pd4,
                                                src, dst, bconst, out, E);
}

// Round 8
// 174.130 us; speedup vs baseline: 12.8178x; 1.1858x over previous
//
#include <hip/hip_runtime.h>
#include <hip/hip_bf16.h>

// ---------------------------------------------------------------------------
// GraphSAGE 2-layer (mean agg) + edge MLP predictor.
// Round 8: atomic-free CSR build (counting sort over dst>>8 buckets, LDS-only
// atomics) replaces k_deg/k_scan/k_fill + memset. Everything else = round 7.
// score[e] = ps[src] + pd[dst] + bconst,
//   ps[n] = P[n].u + mean_in(P[src].t),  pd[n] = P[n].v + mean_in(P[src].w)
// ---------------------------------------------------------------------------

typedef __attribute__((ext_vector_type(8))) short bf16x8;
typedef __attribute__((ext_vector_type(4))) float f32x4;

static __device__ __forceinline__ float bf16lo(unsigned u) {
    return __uint_as_float(u << 16);
}
static __device__ __forceinline__ float bf16hi(unsigned u) {
    return __uint_as_float(u & 0xffff0000u);
}
static __device__ __forceinline__ unsigned short f2bf(float f) {
    unsigned u = __float_as_uint(f);
    unsigned r = 0x7fffu + ((u >> 16) & 1u);  // round to nearest even
    return (unsigned short)((u + r) >> 16);
}
static __device__ __forceinline__ unsigned pack_bf162(float a, float b) {
    return (unsigned)f2bf(a) | ((unsigned)f2bf(b) << 16);
}

#define SORT_BLOCKS 256   // S1/S3 chunk blocks

// ---------------- fused misc: cvt | S1 bucket-hist | Wt1 prep | Wc prep -----
__global__ __launch_bounds__(256) void k_misc(
    const float* __restrict__ x, unsigned short* __restrict__ xb,
    const int* __restrict__ dst, int* __restrict__ H,
    const float* __restrict__ W1s, const float* __restrict__ W1n,
    unsigned short* __restrict__ Wt1,
    const float* __restrict__ W2s, const float* __restrict__ W2n,
    const float* __restrict__ Wp, const float* __restrict__ b2,
    const float* __restrict__ bp, float* __restrict__ Wc,
    float* __restrict__ bconst, int N, int E, int CHUNK)
{
    const int nCvt = (N * 32 + 255) / 256;
    const int b = blockIdx.x;
    const int t = threadIdx.x;

    if (b < nCvt) {
        int i = b * 256 + t;
        if (i < N * 32) {
            float4 v = ((const float4*)x)[i];
            uint2 o;
            o.x = pack_bf162(v.x, v.y);
            o.y = pack_bf162(v.z, v.w);
            *(uint2*)(xb + (size_t)i * 4) = o;
        }
    } else if (b < nCvt + SORT_BLOCKS) {
        // S1: LDS histogram of dst>>8 for this block's edge chunk
        __shared__ int hist[256];
        hist[t] = 0;
        __syncthreads();
        int blk = b - nCvt;
        int start = blk * CHUNK;
        int end = min(start + CHUNK, E);
        for (int e = start + t; e < end; e += 256)
            atomicAdd(&hist[((unsigned)dst[e]) >> 8], 1);
        __syncthreads();
        H[blk * 256 + t] = hist[t];
    } else if (b < nCvt + SORT_BLOCKS + 128) {
        int id = (b - nCvt - SORT_BLOCKS) * 256 + t;  // 32768 total
        int k = id >> 7, n = id & 127;
        float v = (k < 128) ? W1s[k * 128 + n] : W1n[(k - 128) * 128 + n];
        Wt1[n * 256 + k] = f2bf(v);
    } else {
        // Wc[c][j]: j 0-2 u=W2s@Wp_top, 3-5 t=W2n@Wp_top,
        //             6-8 v=W2s@Wp_bot, 9-11 w=W2n@Wp_bot; bconst
        for (int id = t; id < 1539; id += 256) {
            if (id < 1536) {
                int c = id / 12, j = id % 12;
                int q = j / 3, jj = j % 3;
                const float* W2 = (q == 0 || q == 2) ? W2s : W2n;
                int wpoff = (q < 2) ? 0 : 128;
                float s = 0.f;
                for (int m = 0; m < 128; ++m)
                    s += W2[c * 128 + m] * Wp[(wpoff + m) * 3 + jj];
                Wc[c * 12 + j] = s;
            } else {
                int jj = id - 1536;
                float s = bp[jj];
                for (int m = 0; m < 128; ++m)
                    s += b2[m] * (Wp[m * 3 + jj] + Wp[(128 + m) * 3 + jj]);
                bconst[jj] = s;
            }
        }
    }
}

// ---------------- S2: scan histograms -> per-(block,bin) offsets ------------
// One block. Converts H in place to exclusive base offsets; emits bucketBase.
__global__ __launch_bounds__(256) void k_s2(int* __restrict__ H,
                                            int* __restrict__ bucketBase,
                                            int NB, int E) {
    const int t = threadIdx.x;
    int tot = 0;
    for (int blk = 0; blk < SORT_BLOCKS; ++blk) tot += H[blk * 256 + t];
    __shared__ int lt[256];
    lt[t] = tot;
    __syncthreads();
    for (int off = 1; off < 256; off <<= 1) {
        int u = (t >= off) ? lt[t - off] : 0;
        __syncthreads();
        lt[t] += u;
        __syncthreads();
    }
    int excl = lt[t] - tot;
    if (t < NB) bucketBase[t] = excl;
    if (t == 0) bucketBase[NB] = E;
    int run = excl;
    for (int blk = 0; blk < SORT_BLOCKS; ++blk) {
        int h = H[blk * 256 + t];
        H[blk * 256 + t] = run;
        run += h;
    }
}

// ---------------- S3: scatter edges into bucket regions (LDS cursors) -------
__global__ __launch_bounds__(256) void k_s3(const int* __restrict__ src,
                                            const int* __restrict__ dst,
                                            const int* __restrict__ H,
                                            int* __restrict__ packed,
                                            int E, int CHUNK) {
    __shared__ int cur[256];
    const int t = threadIdx.x, blk = blockIdx.x;
    cur[t] = H[blk * 256 + t];
    __syncthreads();
    int start = blk * CHUNK, end = min(start + CHUNK, E);
    for (int e = start + t; e < end; e += 256) {
        int d = dst[e];
        int p = atomicAdd(&cur[((unsigned)d) >> 8], 1);
        packed[p] = (src[e] & 0xFFFF) | ((d & 255) << 16);  // N<=65536
    }
}

// ---------------- S4: per-bucket counting sort + CSR finalize ---------------
// Block b owns nodes [b*256, b*256+256) and edge region [bucketBase[b], [b+1]).
// Emits eidx (dst-sorted src list), cursor (END offsets), fdeg, invdeg.
__global__ __launch_bounds__(256) void k_s4(const int* __restrict__ packed,
                                            const int* __restrict__ bucketBase,
                                            int* __restrict__ eidx,
                                            int* __restrict__ cursor,
                                            float* __restrict__ fdeg,
                                            float* __restrict__ invdeg, int N) {
    const int t = threadIdx.x, b = blockIdx.x;
    const int rb = bucketBase[b], re = bucketBase[b + 1];
    __shared__ int cnt[256];
    __shared__ int lt[256];
    __shared__ int cur[256];
    cnt[t] = 0;
    __syncthreads();
    for (int i = rb + t; i < re; i += 256)
        atomicAdd(&cnt[(packed[i] >> 16) & 255], 1);
    __syncthreads();
    int v = cnt[t];
    lt[t] = v;
    __syncthreads();
    for (int off = 1; off < 256; off <<= 1) {
        int u = (t >= off) ? lt[t - off] : 0;
        __syncthreads();
        lt[t] += u;
        __syncthreads();
    }
    int excl = lt[t] - v;
    int node = b * 256 + t;
    if (node < N) {
        cursor[node] = rb + excl + v;  // end offset (round-7 convention)
        fdeg[node] = (float)v;
        invdeg[node] = 1.0f / fmaxf((float)v, 1.0f);
    }
    cur[t] = rb + excl;
    __syncthreads();
    for (int i = rb + t; i < re; i += 256) {
        int p = packed[i];
        int pos = atomicAdd(&cur[(p >> 16) & 255], 1);
        eidx[pos] = p & 0xFFFF;
    }
}

// ---------------- fused gather-aggregate + MFMA GEMM + projection -----------
// Per wave: 32 nodes (r0=nodeBase+lrow, r1=r0+16). Lane (lrow,lk) aggregates
// agg dims {ksb*32+lk*8+0..7} of its 2 nodes in fp32 regs (gathered from xb),
// packs to bf16 MFMA A-fragments for ks=4..7. ks=0..3 A-fragments read xb.
// h = relu(...) lives in registers; P[n][12] = h @ Wc via 16-lane allreduce.
__global__ __launch_bounds__(256) void k_gemm_fused(
    const unsigned short* __restrict__ xb,
    const int* __restrict__ eidx, const int* __restrict__ cursor,
    const float* __restrict__ fdeg, const float* __restrict__ invdeg,
    const unsigned short* __restrict__ Wt, const float* __restrict__ bias,
    const float* __restrict__ Wc, float* __restrict__ P, int N)
{
    __shared__ __align__(16) char sW[65536];  // Wt swizzled: 128 rows x 512B
    __shared__ float sWc[1536];
    const int t = threadIdx.x;

#pragma unroll
    for (int i = 0; i < 16; ++i) {
        int o = (i * 256 + t) * 16;
        int n = o >> 9;
        int c = o & 511;
        int sw = (n << 9) | (c ^ ((n & 7) << 4));
        *(float4*)&sW[sw] = *(const float4*)((const char*)Wt + o);
    }
    for (int i = t; i < 1536; i += 256) sWc[i] = Wc[i];

    const int wave = t >> 6, lane = t & 63;
    const int nodeBase = blockIdx.x * 128 + wave * 32;
    const int lrow = lane & 15, lk = lane >> 4;
    const int r0 = nodeBase + lrow, r1 = nodeBase + 16 + lrow;

    union { bf16x8 v; unsigned u[4]; } afrag0[4], afrag1[4];

    // ---- register-space aggregation for r0, r1 ----
    {
        float agg[4][8];
#pragma unroll
        for (int ksb = 0; ksb < 4; ++ksb)
#pragma unroll
            for (int i = 0; i < 8; ++i) agg[ksb][i] = 0.f;
        if (r0 < N) {
            int d = (int)fdeg[r0], o = cursor[r0] - d;
            for (int j = 0; j < d; ++j) {
                int s = eidx[o + j];
                const unsigned short* row = xb + (size_t)s * 128 + lk * 8;
#pragma unroll
                for (int ksb = 0; ksb < 4; ++ksb) {
                    uint4 v = *(const uint4*)(row + ksb * 32);
                    agg[ksb][0] += bf16lo(v.x); agg[ksb][1] += bf16hi(v.x);
                    agg[ksb][2] += bf16lo(v.y); agg[ksb][3] += bf16hi(v.y);
                    agg[ksb][4] += bf16lo(v.z); agg[ksb][5] += bf16hi(v.z);
                    agg[ksb][6] += bf16lo(v.w); agg[ksb][7] += bf16hi(v.w);
                }
            }
            float sc = invdeg[r0];
#pragma unroll
            for (int ksb = 0; ksb < 4; ++ksb)
#pragma unroll
                for (int i = 0; i < 4; ++i)
                    afrag0[ksb].u[i] = pack_bf162(agg[ksb][2 * i] * sc,
                                                  agg[ksb][2 * i + 1] * sc);
        } else {
#pragma unroll
            for (int ksb = 0; ksb < 4; ++ksb)
#pragma unroll
                for (int i = 0; i < 4; ++i) afrag0[ksb].u[i] = 0u;
        }
    }
    {
        float agg[4][8];
#pragma unroll
        for (int ksb = 0; ksb < 4; ++ksb)
#pragma unroll
            for (int i = 0; i < 8; ++i) agg[ksb][i] = 0.f;
        if (r1 < N) {
            int d = (int)fdeg[r1], o = cursor[r1] - d;
            for (int j = 0; j < d; ++j) {
                int s = eidx[o + j];
                const unsigned short* row = xb + (size_t)s * 128 + lk * 8;
#pragma unroll
                for (int ksb = 0; ksb < 4; ++ksb) {
                    uint4 v = *(const uint4*)(row + ksb * 32);
                    agg[ksb][0] += bf16lo(v.x); agg[ksb][1] += bf16hi(v.x);
                    agg[ksb][2] += bf16lo(v.y); agg[ksb][3] += bf16hi(v.y);
                    agg[ksb][4] += bf16lo(v.z); agg[ksb][5] += bf16hi(v.z);
                    agg[ksb][6] += bf16lo(v.w); agg[ksb][7] += bf16hi(v.w);
                }
            }
            float sc = invdeg[r1];
#pragma unroll
            for (int ksb = 0; ksb < 4; ++ksb)
#pragma unroll
                for (int i = 0; i < 4; ++i)
                    afrag1[ksb].u[i] = pack_bf162(agg[ksb][2 * i] * sc,
                                                  agg[ksb][2 * i + 1] * sc);
        } else {
#pragma unroll
            for (int ksb = 0; ksb < 4; ++ksb)
#pragma unroll
                for (int i = 0; i < 4; ++i) afrag1[ksb].u[i] = 0u;
        }
    }

    f32x4 acc[2][8];
#pragma unroll
    for (int rs = 0; rs < 2; ++rs)
#pragma unroll
        for (int nb = 0; nb < 8; ++nb) acc[rs][nb] = (f32x4){0.f, 0.f, 0.f, 0.f};

    __syncthreads();

    for (int ks = 0; ks < 8; ++ks) {
        bf16x8 a0, a1;
        if (ks < 4) {
            const int kk = ks * 32 + lk * 8;
            a0 = (bf16x8){};
            a1 = (bf16x8){};
            if (r0 < N) a0 = *(const bf16x8*)(xb + (size_t)r0 * 128 + kk);
            if (r1 < N) a1 = *(const bf16x8*)(xb + (size_t)r1 * 128 + kk);
        } else {
            a0 = afrag0[ks - 4].v;
            a1 = afrag1[ks - 4].v;
        }
        const int cbase = ks * 64 + lk * 16;  // byte col within 512B row
#pragma unroll
        for (int nb = 0; nb < 8; ++nb) {
            int n = nb * 16 + lrow;
            int sw = (n << 9) | (cbase ^ ((n & 7) << 4));
            bf16x8 b = *(const bf16x8*)&sW[sw];
            acc[0][nb] = __builtin_amdgcn_mfma_f32_16x16x32_bf16(a0, b, acc[0][nb], 0, 0, 0);
            acc[1][nb] = __builtin_amdgcn_mfma_f32_16x16x32_bf16(a1, b, acc[1][nb], 0, 0, 0);
        }
    }

    // Epilogue: C/D layout col = lane&15, row = (lane>>4)*4 + reg [m89].
#pragma unroll
    for (int rs = 0; rs < 2; ++rs) {
        float hval[8][4];
#pragma unroll
        for (int nb = 0; nb < 8; ++nb) {
            float bv = bias[nb * 16 + lrow];
#pragma unroll
            for (int r = 0; r < 4; ++r)
                hval[nb][r] = fmaxf(acc[rs][nb][r] + bv, 0.f);
        }
#pragma unroll
        for (int r = 0; r < 4; ++r) {
            float pj[12];
#pragma unroll
            for (int j = 0; j < 12; ++j) pj[j] = 0.f;
#pragma unroll
            for (int nb = 0; nb < 8; ++nb) {
                float hv = hval[nb][r];
                const float* wrow = &sWc[(nb * 16 + lrow) * 12];
#pragma unroll
                for (int j = 0; j < 12; ++j) pj[j] += hv * wrow[j];
            }
#pragma unroll
            for (int off = 8; off; off >>= 1) {
#pragma unroll
                for (int j = 0; j < 12; ++j) pj[j] += __shfl_xor(pj[j], off, 64);
            }
            int node = nodeBase + rs * 16 + lk * 4 + r;
            if (lrow == 0 && node < N) {
                float* prow = &P[(size_t)node * 16];   // padded to 64B rows
                *(float4*)(prow + 0) = make_float4(pj[0], pj[1], pj[2], pj[3]);
                *(float4*)(prow + 4) = make_float4(pj[4], pj[5], pj[6], pj[7]);
                *(float4*)(prow + 8) = make_float4(pj[8], pj[9], pj[10], pj[11]);
            }
        }
    }
}

// ---------------- 6-dim aggregation + finalize ps/pd -----------------------
__global__ __launch_bounds__(256) void k_agg3(const float* __restrict__ P,
                                              const int* __restrict__ eidx,
                                              const int* __restrict__ cursor,
                                              const float* __restrict__ fdeg,
                                              const float* __restrict__ invdeg,
                                              float* __restrict__ ps4,
                                              float* __restrict__ pd4, int N) {
    int g = (blockIdx.x * blockDim.x + threadIdx.x) >> 3;
    int j = threadIdx.x & 7;
    if (g >= N || j >= 6) return;
    int d = (int)fdeg[g];
    int o = cursor[g] - d;
    int col = (j < 3) ? (3 + j) : (6 + j);  // t: 3..5  w: 9..11
    float a = 0.f;
    for (int i = 0; i < d; ++i) {
        int s = eidx[o + i];
        a += P[(size_t)s * 16 + col];
    }
    a *= invdeg[g];
    if (j < 3)
        ps4[(size_t)g * 4 + j] = P[(size_t)g * 16 + j] + a;           // u + mean(t)
    else
        pd4[(size_t)g * 4 + (j - 3)] = P[(size_t)g * 16 + 3 + j] + a; // v + mean(w)
}

__global__ void k_edge(const float4* __restrict__ ps4, const float4* __restrict__ pd4,
                       const int* __restrict__ src, const int* __restrict__ dst,
                       const float* __restrict__ bconst, float* __restrict__ out, int E)
{
    int e = blockIdx.x * blockDim.x + threadIdx.x;
    if (e >= E) return;
    float4 a = ps4[src[e]];
    float4 b = pd4[dst[e]];
    out[(size_t)e * 3 + 0] = a.x + b.x + bconst[0];
    out[(size_t)e * 3 + 1] = a.y + b.y + bconst[1];
    out[(size_t)e * 3 + 2] = a.z + b.z + bconst[2];
}

extern "C" void kernel_launch(void* const* d_in, const int* in_sizes, int n_in,
                              void* d_out, int out_size, void* d_ws, size_t ws_size,
                              hipStream_t stream)
{
    const float* x   = (const float*)d_in[0];
    // d_in[1] = e (edge features) — unused by the reference score
    const int*   src = (const int*)d_in[2];
    const int*   dst = (const int*)d_in[3];
    const float* W1s = (const float*)d_in[4];
    const float* W1n = (const float*)d_in[5];
    const float* b1  = (const float*)d_in[6];
    const float* W2s = (const float*)d_in[7];
    const float* W2n = (const float*)d_in[8];
    const float* b2  = (const float*)d_in[9];
    const float* Wp  = (const float*)d_in[10];
    const float* bp  = (const float*)d_in[11];
    const int N = in_sizes[0] / 128;
    const int E = in_sizes[2];
    float* out = (float*)d_out;

    const int NB = (N + 255) / 256;            // dst buckets (<=256 for N<=65536)
    const int CHUNK = (E + SORT_BLOCKS - 1) / SORT_BLOCKS;

    // ---- workspace carve (256B aligned chunks) ----
    char* wsp = (char*)d_ws;
    auto alloc = [&](size_t bytes) { char* p = wsp; wsp += (bytes + 255) & ~(size_t)255; return p; };
    float* fdeg     = (float*)alloc((size_t)N * 4);
    float* invdeg   = (float*)alloc((size_t)N * 4);
    int*   cursor   = (int*)alloc((size_t)N * 4);
    int*   eidx     = (int*)alloc((size_t)E * 4);
    int*   packed   = (int*)alloc((size_t)E * 4);
    int*   H        = (int*)alloc((size_t)SORT_BLOCKS * 256 * 4);
    int*   bucketBase = (int*)alloc(260 * 4);
    unsigned short* xb  = (unsigned short*)alloc((size_t)N * 128 * 2);
    unsigned short* Wt1 = (unsigned short*)alloc(256 * 128 * 2);
    float* Wc     = (float*)alloc(1536 * 4);
    float* bconst = (float*)alloc(256);
    float* P      = (float*)alloc((size_t)N * 16 * 4);   // padded 64B rows
    float* ps4    = (float*)alloc((size_t)N * 16);
    float* pd4    = (float*)alloc((size_t)N * 16);

    // fused cvt | S1 bucket-hist | weight prep (all independent)
    const int nCvt = (N * 32 + 255) / 256;
    k_misc<<<nCvt + SORT_BLOCKS + 129, 256, 0, stream>>>(
        x, xb, dst, H, W1s, W1n, Wt1, W2s, W2n, Wp, b2, bp, Wc, bconst, N, E, CHUNK);

    // atomic-free CSR build
    k_s2<<<1, 256, 0, stream>>>(H, bucketBase, NB, E);
    k_s3<<<SORT_BLOCKS, 256, 0, stream>>>(src, dst, H, packed, E, CHUNK);
    k_s4<<<NB, 256, 0, stream>>>(packed, bucketBase, eidx, cursor, fdeg, invdeg, N);

    // layer 1 + projection, fully fused (agg in registers, h never stored)
    k_gemm_fused<<<(N + 127) / 128, 256, 0, stream>>>(xb, eidx, cursor, fdeg, invdeg,
                                                      Wt1, b1, Wc, P, N);

    // layer 2 (factorized): 6-dim aggregation -> ps/pd
    k_agg3<<<(N * 8 + 255) / 256, 256, 0, stream>>>(P, eidx, cursor, fdeg, invdeg,
                                                    ps4, pd4, N);

    // edge scoring
    k_edge<<<(E + 255) / 256, 256, 0, stream>>>((const float4*)ps4, (const float4*)pd4,
                                                src, dst, bconst, out, E);
}

// Round 9
// 161.411 us; speedup vs baseline: 13.8278x; 1.0788x over previous
//
#include <hip/hip_runtime.h>
#include <hip/hip_bf16.h>

// ---------------------------------------------------------------------------
// GraphSAGE 2-layer (mean agg) + edge MLP predictor.
// Round 9: gather-phase latency attack in k_gemm_fused —
//  (a) block's contiguous CSR eidx run staged into LDS (reusing the sW
//      buffer before weights are staged; occupancy unchanged),
//  (b) edge loop unrolled x2 for memory-level parallelism.
// Also: SORT_BLOCKS 256->128 (halves k_s2), P layout self[0..5]/neigh[8..13].
// score[e] = ps[src] + pd[dst] + bconst
// ---------------------------------------------------------------------------

typedef __attribute__((ext_vector_type(8))) short bf16x8;
typedef __attribute__((ext_vector_type(4))) float f32x4;

static __device__ __forceinline__ float bf16lo(unsigned u) {
    return __uint_as_float(u << 16);
}
static __device__ __forceinline__ float bf16hi(unsigned u) {
    return __uint_as_float(u & 0xffff0000u);
}
static __device__ __forceinline__ unsigned short f2bf(float f) {
    unsigned u = __float_as_uint(f);
    unsigned r = 0x7fffu + ((u >> 16) & 1u);  // round to nearest even
    return (unsigned short)((u + r) >> 16);
}
static __device__ __forceinline__ unsigned pack_bf162(float a, float b) {
    return (unsigned)f2bf(a) | ((unsigned)f2bf(b) << 16);
}

#define SORT_BLOCKS 128   // S1/S3 chunk blocks

// ---------------- fused misc: cvt | S1 bucket-hist | Wt1 prep | Wc prep -----
__global__ __launch_bounds__(256) void k_misc(
    const float* __restrict__ x, unsigned short* __restrict__ xb,
    const int* __restrict__ dst, int* __restrict__ H,
    const float* __restrict__ W1s, const float* __restrict__ W1n,
    unsigned short* __restrict__ Wt1,
    const float* __restrict__ W2s, const float* __restrict__ W2n,
    const float* __restrict__ Wp, const float* __restrict__ b2,
    const float* __restrict__ bp, float* __restrict__ Wc,
    float* __restrict__ bconst, int N, int E, int CHUNK)
{
    const int nCvt = (N * 32 + 255) / 256;
    const int b = blockIdx.x;
    const int t = threadIdx.x;

    if (b < nCvt) {
        int i = b * 256 + t;
        if (i < N * 32) {
            float4 v = ((const float4*)x)[i];
            uint2 o;
            o.x = pack_bf162(v.x, v.y);
            o.y = pack_bf162(v.z, v.w);
            *(uint2*)(xb + (size_t)i * 4) = o;
        }
    } else if (b < nCvt + SORT_BLOCKS) {
        // S1: LDS histogram of dst>>8 for this block's edge chunk
        __shared__ int hist[256];
        hist[t] = 0;
        __syncthreads();
        int blk = b - nCvt;
        int start = blk * CHUNK;
        int end = min(start + CHUNK, E);
        for (int e = start + t; e < end; e += 256)
            atomicAdd(&hist[((unsigned)dst[e]) >> 8], 1);
        __syncthreads();
        H[blk * 256 + t] = hist[t];
    } else if (b < nCvt + SORT_BLOCKS + 128) {
        int id = (b - nCvt - SORT_BLOCKS) * 256 + t;  // 32768 total
        int k = id >> 7, n = id & 127;
        float v = (k < 128) ? W1s[k * 128 + n] : W1n[(k - 128) * 128 + n];
        Wt1[n * 256 + k] = f2bf(v);
    } else {
        // Wc[c][j]: j 0-2 u=W2s@Wp_top, 3-5 t=W2n@Wp_top,
        //             6-8 v=W2s@Wp_bot, 9-11 w=W2n@Wp_bot; bconst
        for (int id = t; id < 1539; id += 256) {
            if (id < 1536) {
                int c = id / 12, j = id % 12;
                int q = j / 3, jj = j % 3;
                const float* W2 = (q == 0 || q == 2) ? W2s : W2n;
                int wpoff = (q < 2) ? 0 : 128;
                float s = 0.f;
                for (int m = 0; m < 128; ++m)
                    s += W2[c * 128 + m] * Wp[(wpoff + m) * 3 + jj];
                Wc[c * 12 + j] = s;
            } else {
                int jj = id - 1536;
                float s = bp[jj];
                for (int m = 0; m < 128; ++m)
                    s += b2[m] * (Wp[m * 3 + jj] + Wp[(128 + m) * 3 + jj]);
                bconst[jj] = s;
            }
        }
    }
}

// ---------------- S2: scan histograms -> per-(block,bin) offsets ------------
__global__ __launch_bounds__(256) void k_s2(int* __restrict__ H,
                                            int* __restrict__ bucketBase,
                                            int NB, int E) {
    const int t = threadIdx.x;
    int tot = 0;
    for (int blk = 0; blk < SORT_BLOCKS; ++blk) tot += H[blk * 256 + t];
    __shared__ int lt[256];
    lt[t] = tot;
    __syncthreads();
    for (int off = 1; off < 256; off <<= 1) {
        int u = (t >= off) ? lt[t - off] : 0;
        __syncthreads();
        lt[t] += u;
        __syncthreads();
    }
    int excl = lt[t] - tot;
    if (t < NB) bucketBase[t] = excl;
    if (t == 0) bucketBase[NB] = E;
    int run = excl;
    for (int blk = 0; blk < SORT_BLOCKS; ++blk) {
        int h = H[blk * 256 + t];
        H[blk * 256 + t] = run;
        run += h;
    }
}

// ---------------- S3: scatter edges into bucket regions (LDS cursors) -------
__global__ __launch_bounds__(256) void k_s3(const int* __restrict__ src,
                                            const int* __restrict__ dst,
                                            const int* __restrict__ H,
                                            int* __restrict__ packed,
                                            int E, int CHUNK) {
    __shared__ int cur[256];
    const int t = threadIdx.x, blk = blockIdx.x;
    cur[t] = H[blk * 256 + t];
    __syncthreads();
    int start = blk * CHUNK, end = min(start + CHUNK, E);
    for (int e = start + t; e < end; e += 256) {
        int d = dst[e];
        int p = atomicAdd(&cur[((unsigned)d) >> 8], 1);
        packed[p] = (src[e] & 0xFFFF) | ((d & 255) << 16);  // N<=65536
    }
}

// ---------------- S4: per-bucket counting sort + CSR finalize ---------------
__global__ __launch_bounds__(256) void k_s4(const int* __restrict__ packed,
                                            const int* __restrict__ bucketBase,
                                            int* __restrict__ eidx,
                                            int* __restrict__ cursor,
                                            float* __restrict__ fdeg,
                                            float* __restrict__ invdeg, int N) {
    const int t = threadIdx.x, b = blockIdx.x;
    const int rb = bucketBase[b], re = bucketBase[b + 1];
    __shared__ int cnt[256];
    __shared__ int lt[256];
    __shared__ int cur[256];
    cnt[t] = 0;
    __syncthreads();
    for (int i = rb + t; i < re; i += 256)
        atomicAdd(&cnt[(packed[i] >> 16) & 255], 1);
    __syncthreads();
    int v = cnt[t];
    lt[t] = v;
    __syncthreads();
    for (int off = 1; off < 256; off <<= 1) {
        int u = (t >= off) ? lt[t - off] : 0;
        __syncthreads();
        lt[t] += u;
        __syncthreads();
    }
    int excl = lt[t] - v;
    int node = b * 256 + t;
    if (node < N) {
        cursor[node] = rb + excl + v;  // end offset
        fdeg[node] = (float)v;
        invdeg[node] = 1.0f / fmaxf((float)v, 1.0f);
    }
    cur[t] = rb + excl;
    __syncthreads();
    for (int i = rb + t; i < re; i += 256) {
        int p = packed[i];
        int pos = atomicAdd(&cur[(p >> 16) & 255], 1);
        eidx[pos] = p & 0xFFFF;
    }
}

// ---------------- fused gather-aggregate + MFMA GEMM + projection -----------
// Phase A: stage this block's contiguous eidx run into LDS (reuses sW space);
//          lane (lrow,lk) aggregates dims {ksb*32+lk*8..+7} of nodes r0,r1
//          in fp32 regs (2-edge unrolled gather), packs bf16 A-fragments.
// Phase B: stage Wt swizzled + Wc; MFMA; epilogue projects h -> P.
__global__ __launch_bounds__(256) void k_gemm_fused(
    const unsigned short* __restrict__ xb,
    const int* __restrict__ eidx, const int* __restrict__ cursor,
    const float* __restrict__ fdeg, const float* __restrict__ invdeg,
    const unsigned short* __restrict__ Wt, const float* __restrict__ bias,
    const float* __restrict__ Wc, float* __restrict__ P, int N)
{
    __shared__ __align__(16) char sW[65536];  // phase A: eidx cache; B: Wt
    __shared__ float sWc[1536];
    const int t = threadIdx.x;
    const int wave = t >> 6, lane = t & 63;
    const int nodeBase = blockIdx.x * 128 + wave * 32;
    const int lrow = lane & 15, lk = lane >> 4;
    const int r0 = nodeBase + lrow, r1 = nodeBase + 16 + lrow;

    // ---- phase A: stage eidx run ----
    int* eidxL = (int*)sW;                       // 16384 entries
    const int nb0 = blockIdx.x * 128;
    const int lastN = min(nb0 + 127, N - 1);
    const int estart = cursor[nb0] - (int)fdeg[nb0];
    const int eend = cursor[lastN];
    const int ecnt = eend - estart;
    const bool ldsOK = (ecnt <= 16384);
    if (ldsOK) {
        for (int i = t; i < ecnt; i += 256) eidxL[i] = eidx[estart + i];
    }
    __syncthreads();

    union { bf16x8 v; unsigned u[4]; } afrag0[4], afrag1[4];

#define GATHER_NODE(R, EP, OFF, AF)                                          \
    {                                                                        \
        float agg[4][8];                                                     \
        _Pragma("unroll") for (int ksb = 0; ksb < 4; ++ksb)                  \
            _Pragma("unroll") for (int i = 0; i < 8; ++i) agg[ksb][i] = 0.f; \
        if ((R) < N) {                                                       \
            int d = (int)fdeg[R];                                            \
            int o = (OFF);                                                   \
            int j = 0;                                                       \
            for (; j + 2 <= d; j += 2) {                                     \
                int s0 = (EP)[o + j], s1 = (EP)[o + j + 1];                  \
                const unsigned short* row0 = xb + (size_t)s0 * 128 + lk * 8; \
                const unsigned short* row1 = xb + (size_t)s1 * 128 + lk * 8; \
                uint4 v0[4], v1[4];                                          \
                _Pragma("unroll") for (int ksb = 0; ksb < 4; ++ksb) {        \
                    v0[ksb] = *(const uint4*)(row0 + ksb * 32);              \
                    v1[ksb] = *(const uint4*)(row1 + ksb * 32);              \
                }                                                            \
                _Pragma("unroll") for (int ksb = 0; ksb < 4; ++ksb) {        \
                    agg[ksb][0] += bf16lo(v0[ksb].x);                        \
                    agg[ksb][1] += bf16hi(v0[ksb].x);                        \
                    agg[ksb][2] += bf16lo(v0[ksb].y);                        \
                    agg[ksb][3] += bf16hi(v0[ksb].y);                        \
                    agg[ksb][4] += bf16lo(v0[ksb].z);                        \
                    agg[ksb][5] += bf16hi(v0[ksb].z);                        \
                    agg[ksb][6] += bf16lo(v0[ksb].w);                        \
                    agg[ksb][7] += bf16hi(v0[ksb].w);                        \
                    agg[ksb][0] += bf16lo(v1[ksb].x);                        \
                    agg[ksb][1] += bf16hi(v1[ksb].x);                        \
                    agg[ksb][2] += bf16lo(v1[ksb].y);                        \
                    agg[ksb][3] += bf16hi(v1[ksb].y);                        \
                    agg[ksb][4] += bf16lo(v1[ksb].z);                        \
                    agg[ksb][5] += bf16hi(v1[ksb].z);                        \
                    agg[ksb][6] += bf16lo(v1[ksb].w);                        \
                    agg[ksb][7] += bf16hi(v1[ksb].w);                        \
                }                                                            \
            }                                                                \
            if (j < d) {                                                     \
                int s0 = (EP)[o + j];                                        \
                const unsigned short* row0 = xb + (size_t)s0 * 128 + lk * 8; \
                _Pragma("unroll") for (int ksb = 0; ksb < 4; ++ksb) {        \
                    uint4 v0 = *(const uint4*)(row0 + ksb * 32);             \
                    agg[ksb][0] += bf16lo(v0.x);                             \
                    agg[ksb][1] += bf16hi(v0.x);                             \
                    agg[ksb][2] += bf16lo(v0.y);                             \
                    agg[ksb][3] += bf16hi(v0.y);                             \
                    agg[ksb][4] += bf16lo(v0.z);                             \
                    agg[ksb][5] += bf16hi(v0.z);                             \
                    agg[ksb][6] += bf16lo(v0.w);                             \
                    agg[ksb][7] += bf16hi(v0.w);                             \
                }                                                            \
            }                                                                \
            float sc = invdeg[R];                                            \
            _Pragma("unroll") for (int ksb = 0; ksb < 4; ++ksb)              \
                _Pragma("unroll") for (int i = 0; i < 4; ++i)                \
                    AF[ksb].u[i] = pack_bf162(agg[ksb][2 * i] * sc,          \
                                              agg[ksb][2 * i + 1] * sc);     \
        } else {                                                             \
            _Pragma("unroll") for (int ksb = 0; ksb < 4; ++ksb)              \
                _Pragma("unroll") for (int i = 0; i < 4; ++i)                \
                    AF[ksb].u[i] = 0u;                                       \
        }                                                                    \
    }

    if (ldsOK) {
        GATHER_NODE(r0, eidxL, (r0 < N ? cursor[r0] - (int)fdeg[r0] - estart : 0), afrag0)
        GATHER_NODE(r1, eidxL, (r1 < N ? cursor[r1] - (int)fdeg[r1] - estart : 0), afrag1)
    } else {
        GATHER_NODE(r0, eidx, (r0 < N ? cursor[r0] - (int)fdeg[r0] : 0), afrag0)
        GATHER_NODE(r1, eidx, (r1 < N ? cursor[r1] - (int)fdeg[r1] : 0), afrag1)
    }
#undef GATHER_NODE

    // ---- phase B: stage weights over the eidx cache ----
    __syncthreads();
#pragma unroll
    for (int i = 0; i < 16; ++i) {
        int o = (i * 256 + t) * 16;
        int n = o >> 9;
        int c = o & 511;
        int sw = (n << 9) | (c ^ ((n & 7) << 4));
        *(float4*)&sW[sw] = *(const float4*)((const char*)Wt + o);
    }
    for (int i = t; i < 1536; i += 256) sWc[i] = Wc[i];

    f32x4 acc[2][8];
#pragma unroll
    for (int rs = 0; rs < 2; ++rs)
#pragma unroll
        for (int nb = 0; nb < 8; ++nb) acc[rs][nb] = (f32x4){0.f, 0.f, 0.f, 0.f};

    __syncthreads();

    for (int ks = 0; ks < 8; ++ks) {
        bf16x8 a0, a1;
        if (ks < 4) {
            const int kk = ks * 32 + lk * 8;
            a0 = (bf16x8){};
            a1 = (bf16x8){};
            if (r0 < N) a0 = *(const bf16x8*)(xb + (size_t)r0 * 128 + kk);
            if (r1 < N) a1 = *(const bf16x8*)(xb + (size_t)r1 * 128 + kk);
        } else {
            a0 = afrag0[ks - 4].v;
            a1 = afrag1[ks - 4].v;
        }
        const int cbase = ks * 64 + lk * 16;  // byte col within 512B row
#pragma unroll
        for (int nb = 0; nb < 8; ++nb) {
            int n = nb * 16 + lrow;
            int sw = (n << 9) | (cbase ^ ((n & 7) << 4));
            bf16x8 b = *(const bf16x8*)&sW[sw];
            acc[0][nb] = __builtin_amdgcn_mfma_f32_16x16x32_bf16(a0, b, acc[0][nb], 0, 0, 0);
            acc[1][nb] = __builtin_amdgcn_mfma_f32_16x16x32_bf16(a1, b, acc[1][nb], 0, 0, 0);
        }
    }

    // Epilogue: C/D layout col = lane&15, row = (lane>>4)*4 + reg [m89].
    // P row layout: self u0..2,v0..2 at [0..5]; neigh t0..2,w0..2 at [8..13].
#pragma unroll
    for (int rs = 0; rs < 2; ++rs) {
        float hval[8][4];
#pragma unroll
        for (int nb = 0; nb < 8; ++nb) {
            float bv = bias[nb * 16 + lrow];
#pragma unroll
            for (int r = 0; r < 4; ++r)
                hval[nb][r] = fmaxf(acc[rs][nb][r] + bv, 0.f);
        }
#pragma unroll
        for (int r = 0; r < 4; ++r) {
            float pj[12];
#pragma unroll
            for (int j = 0; j < 12; ++j) pj[j] = 0.f;
#pragma unroll
            for (int nb = 0; nb < 8; ++nb) {
                float hv = hval[nb][r];
                const float* wrow = &sWc[(nb * 16 + lrow) * 12];
#pragma unroll
                for (int j = 0; j < 12; ++j) pj[j] += hv * wrow[j];
            }
#pragma unroll
            for (int off = 8; off; off >>= 1) {
#pragma unroll
                for (int j = 0; j < 12; ++j) pj[j] += __shfl_xor(pj[j], off, 64);
            }
            int node = nodeBase + rs * 16 + lk * 4 + r;
            if (lrow == 0 && node < N) {
                float* prow = &P[(size_t)node * 16];
                *(float4*)(prow + 0)  = make_float4(pj[0], pj[1], pj[2], pj[6]);
                *(float4*)(prow + 4)  = make_float4(pj[7], pj[8], 0.f, 0.f);
                *(float4*)(prow + 8)  = make_float4(pj[3], pj[4], pj[5], pj[9]);
                *(float4*)(prow + 12) = make_float4(pj[10], pj[11], 0.f, 0.f);
            }
        }
    }
}

// ---------------- 6-dim aggregation + finalize ps/pd -----------------------
// 8 lanes per node; lane j<6: result_j = P[g][j] + mean_in(P[src][8+j]).
__global__ __launch_bounds__(256) void k_agg3(const float* __restrict__ P,
                                              const int* __restrict__ eidx,
                                              const int* __restrict__ cursor,
                                              const float* __restrict__ fdeg,
                                              const float* __restrict__ invdeg,
                                              float* __restrict__ ps4,
                                              float* __restrict__ pd4, int N) {
    int g = (blockIdx.x * blockDim.x + threadIdx.x) >> 3;
    int j = threadIdx.x & 7;
    if (g >= N || j >= 6) return;
    int d = (int)fdeg[g];
    int o = cursor[g] - d;
    float a = 0.f;
    int i = 0;
    for (; i + 2 <= d; i += 2) {
        int s0 = eidx[o + i], s1 = eidx[o + i + 1];
        a += P[(size_t)s0 * 16 + 8 + j];
        a += P[(size_t)s1 * 16 + 8 + j];
    }
    if (i < d) a += P[(size_t)eidx[o + i] * 16 + 8 + j];
    a *= invdeg[g];
    float r = P[(size_t)g * 16 + j] + a;
    if (j < 3)
        ps4[(size_t)g * 4 + j] = r;
    else
        pd4[(size_t)g * 4 + (j - 3)] = r;
}

__global__ void k_edge(const float4* __restrict__ ps4, const float4* __restrict__ pd4,
                       const int* __restrict__ src, const int* __restrict__ dst,
                       const float* __restrict__ bconst, float* __restrict__ out, int E)
{
    int e = blockIdx.x * blockDim.x + threadIdx.x;
    if (e >= E) return;
    float4 a = ps4[src[e]];
    float4 b = pd4[dst[e]];
    out[(size_t)e * 3 + 0] = a.x + b.x + bconst[0];
    out[(size_t)e * 3 + 1] = a.y + b.y + bconst[1];
    out[(size_t)e * 3 + 2] = a.z + b.z + bconst[2];
}

extern "C" void kernel_launch(void* const* d_in, const int* in_sizes, int n_in,
                              void* d_out, int out_size, void* d_ws, size_t ws_size,
                              hipStream_t stream)
{
    const float* x   = (const float*)d_in[0];
    // d_in[1] = e (edge features) — unused by the reference score
    const int*   src = (const int*)d_in[2];
    const int*   dst = (const int*)d_in[3];
    const float* W1s = (const float*)d_in[4];
    const float* W1n = (const float*)d_in[5];
    const float* b1  = (const float*)d_in[6];
    const float* W2s = (const float*)d_in[7];
    const float* W2n = (const float*)d_in[8];
    const float* b2  = (const float*)d_in[9];
    const float* Wp  = (const float*)d_in[10];
    const float* bp  = (const float*)d_in[11];
    const int N = in_sizes[0] / 128;
    const int E = in_sizes[2];
    float* out = (float*)d_out;

    const int NB = (N + 255) / 256;            // dst buckets (<=256 for N<=65536)
    const int CHUNK = (E + SORT_BLOCKS - 1) / SORT_BLOCKS;

    // ---- workspace carve (256B aligned chunks) ----
    char* wsp = (char*)d_ws;
    auto alloc = [&](size_t bytes) { char* p = wsp; wsp += (bytes + 255) & ~(size_t)255; return p; };
    float* fdeg     = (float*)alloc((size_t)N * 4);
    float* invdeg   = (float*)alloc((size_t)N * 4);
    int*   cursor   = (int*)alloc((size_t)N * 4);
    int*   eidx     = (int*)alloc((size_t)E * 4);
    int*   packed   = (int*)alloc((size_t)E * 4);
    int*   H        = (int*)alloc((size_t)SORT_BLOCKS * 256 * 4);
    int*   bucketBase = (int*)alloc(260 * 4);
    unsigned short* xb  = (unsigned short*)alloc((size_t)N * 128 * 2);
    unsigned short* Wt1 = (unsigned short*)alloc(256 * 128 * 2);
    float* Wc     = (float*)alloc(1536 * 4);
    float* bconst = (float*)alloc(256);
    float* P      = (float*)alloc((size_t)N * 16 * 4);   // padded 64B rows
    float* ps4    = (float*)alloc((size_t)N * 16);
    float* pd4    = (float*)alloc((size_t)N * 16);

    // fused cvt | S1 bucket-hist | weight prep (all independent)
    const int nCvt = (N * 32 + 255) / 256;
    k_misc<<<nCvt + SORT_BLOCKS + 129, 256, 0, stream>>>(
        x, xb, dst, H, W1s, W1n, Wt1, W2s, W2n, Wp, b2, bp, Wc, bconst, N, E, CHUNK);

    // atomic-free CSR build
    k_s2<<<1, 256, 0, stream>>>(H, bucketBase, NB, E);
    k_s3<<<SORT_BLOCKS, 256, 0, stream>>>(src, dst, H, packed, E, CHUNK);
    k_s4<<<NB, 256, 0, stream>>>(packed, bucketBase, eidx, cursor, fdeg, invdeg, N);

    // layer 1 + projection, fully fused (agg in registers, h never stored)
    k_gemm_fused<<<(N + 127) / 128, 256, 0, stream>>>(xb, eidx, cursor, fdeg, invdeg,
                                                      Wt1, b1, Wc, P, N);

    // layer 2 (factorized): 6-dim aggregation -> ps/pd
    k_agg3<<<(N * 8 + 255) / 256, 256, 0, stream>>>(P, eidx, cursor, fdeg, invdeg,
                                                    ps4, pd4, N);

    // edge scoring
    k_edge<<<(E + 255) / 256, 256, 0, stream>>>((const float4*)ps4, (const float4*)pd4,
                                                src, dst, bconst, out, E);
}